// Round 1
// baseline (5301.188 us; speedup 1.0000x reference)
//
#include <hip/hip_runtime.h>
#include <math.h>

#define LRELU_SLOPE 0.01f
#define BN_EPS 1e-5f
#define CI_CHUNK 4

__device__ __forceinline__ float lrelu_f(float v) { return v >= 0.f ? v : LRELU_SLOPE * v; }

// Tiled direct 3x3 conv, fp32.
// Block = 256 threads. Output tile = 8x8 pixels x (16*KCO) channels.
// Thread (tx = tid&15, ty = tid>>4): computes KCO cos x 4 consecutive-x pixels.
// MODE: 0 = plain conv (+bias, optional lrelu)            (Hin==Ho)
//       1 = conv + lrelu + down2 fused (keep even coords) (Ho==Hin/2)
//       2 = zero-insert up2 + conv + lrelu                (Hin,Win = SMALL dims, Ho==2*Hin)
//       3 = MODE2 with Cout==64, then fused 1x1 (64->3) epilogue written to out
template <int MODE, int KCO>
__global__ __launch_bounds__(256) void conv3_kernel(
    const float* __restrict__ in, const float* __restrict__ wgt,
    const float* __restrict__ bias, float* __restrict__ out,
    int Cin, int Hin, int Win, int Cout, int Ho, int Wo, int apply_act,
    const float* __restrict__ w_ep, const float* __restrict__ b_ep)
{
  constexpr int IH = (MODE == 1) ? 17 : 10;   // staged input tile height/width
  constexpr int IP = (MODE == 1) ? 18 : 12;   // LDS pitch (pad: conflicts <=2-way, free)
  __shared__ float s_in[CI_CHUNK * IH * IP];
  __shared__ float s_w[64 * 37];              // [co][e], pitch 37 -> conflict-free-ish
  __shared__ float s_t2[(MODE == 3) ? 64 * 64 : 1];
  __shared__ float s_wep[(MODE == 3) ? 192 : 1];

  const int tid  = threadIdx.x;
  const int tx   = tid & 15;
  const int ty   = tid >> 4;
  const int trow = ty >> 1;          // 0..7   (tile row)
  const int xl0  = (ty & 1) * 4;     // 0 or 4 (tile col base)

  const int tilesX = Wo >> 3;
  const int x0   = (blockIdx.x % tilesX) * 8;
  const int y0   = (blockIdx.x / tilesX) * 8;
  const int cog0 = blockIdx.y * (16 * KCO);
  const int n    = blockIdx.z;

  const size_t HWin = (size_t)Hin * Win;
  const float* inN = in + (size_t)n * Cin * HWin;

  if (MODE == 3) {
    if (tid < 192) s_wep[tid] = w_ep[tid];
  }

  float acc[KCO][4];
#pragma unroll
  for (int a = 0; a < KCO; a++)
#pragma unroll
    for (int b = 0; b < 4; b++) acc[a][b] = 0.f;

  for (int ci0 = 0; ci0 < Cin; ci0 += CI_CHUNK) {
    const int chunk = (Cin - ci0 < CI_CHUNK) ? (Cin - ci0) : CI_CHUNK;
    __syncthreads();   // protect previous iteration's reads
    // ---- stage input tile (with SAME zero-padding; MODE2/3 materialize zero-insertion) ----
    const int tot = chunk * (IH * IH);
    for (int idx = tid; idx < tot; idx += 256) {
      const int ci  = idx / (IH * IH);
      const int rem = idx - ci * (IH * IH);
      const int r   = rem / IH;
      const int c   = rem - r * IH;
      float v = 0.f;
      if (MODE == 1) {
        const int gy = 2 * y0 - 1 + r;
        const int gx = 2 * x0 - 1 + c;
        if (gy >= 0 && gy < Hin && gx >= 0 && gx < Win)
          v = inN[(size_t)(ci0 + ci) * HWin + (size_t)gy * Win + gx];
      } else if (MODE == 0) {
        const int gy = y0 - 1 + r;
        const int gx = x0 - 1 + c;
        if (gy >= 0 && gy < Hin && gx >= 0 && gx < Win)
          v = inN[(size_t)(ci0 + ci) * HWin + (size_t)gy * Win + gx];
      } else {  // MODE 2/3: logical zero-inserted coords over (2Hin, 2Win)
        const int ly = y0 - 1 + r;
        const int lx = x0 - 1 + c;
        if (ly >= 0 && lx >= 0 && ((ly & 1) == 0) && ((lx & 1) == 0)) {
          const int gy = ly >> 1, gx = lx >> 1;
          if (gy < Hin && gx < Win)
            v = inN[(size_t)(ci0 + ci) * HWin + (size_t)gy * Win + gx];
        }
      }
      s_in[(ci * IH + r) * IP + c] = v;
    }
    // ---- stage weights: global [co][ci][3][3] -> LDS [co][e], e = ci*9+tap (coalesced) ----
    const int e9 = chunk * 9;
    const int wtot = e9 * (16 * KCO);
    for (int idx = tid; idx < wtot; idx += 256) {
      const int co = idx / e9;
      const int e  = idx - co * e9;
      s_w[co * 37 + e] = wgt[(size_t)(cog0 + co) * Cin * 9 + (size_t)ci0 * 9 + e];
    }
    __syncthreads();

    auto body = [&](int ci) {
#pragma unroll
      for (int ky = 0; ky < 3; ky++) {
        const float* rp;
        if (MODE == 1) rp = &s_in[(ci * IH + 2 * trow + ky) * IP + 2 * xl0];
        else           rp = &s_in[(ci * IH + trow + ky) * IP + xl0];
        float iv[(MODE == 1) ? 9 : 6];
#pragma unroll
        for (int i = 0; i < ((MODE == 1) ? 9 : 6); i++) iv[i] = rp[i];
#pragma unroll
        for (int kx = 0; kx < 3; kx++) {
          const int e = ci * 9 + ky * 3 + kx;
          float wv[KCO];
#pragma unroll
          for (int k = 0; k < KCO; k++) wv[k] = s_w[(tx * KCO + k) * 37 + e];
#pragma unroll
          for (int j = 0; j < 4; j++) {
            const float xv = (MODE == 1) ? iv[2 * j + kx] : iv[j + kx];
#pragma unroll
            for (int k = 0; k < KCO; k++) acc[k][j] += wv[k] * xv;
          }
        }
      }
    };
    if (chunk == CI_CHUNK) {
#pragma unroll
      for (int ci = 0; ci < CI_CHUNK; ci++) body(ci);
    } else {
      for (int ci = 0; ci < chunk; ci++) body(ci);  // only d0 (Cin=3)
    }
  }

  if (MODE != 3) {
#pragma unroll
    for (int k = 0; k < KCO; k++) {
      const int co = cog0 + tx * KCO + k;
      const float b = bias[co];
      float4 v;
      v.x = acc[k][0] + b; v.y = acc[k][1] + b; v.z = acc[k][2] + b; v.w = acc[k][3] + b;
      if (apply_act) { v.x = lrelu_f(v.x); v.y = lrelu_f(v.y); v.z = lrelu_f(v.z); v.w = lrelu_f(v.w); }
      float* op = out + ((size_t)((size_t)n * Cout + co) * Ho + (y0 + trow)) * Wo + x0 + xl0;
      *reinterpret_cast<float4*>(op) = v;
    }
  } else {
    // phase 1: bias + lrelu, park 64ch x 64pix tile in LDS
#pragma unroll
    for (int k = 0; k < KCO; k++) {
      const int co = tx * KCO + k;
      const float b = bias[co];
#pragma unroll
      for (int j = 0; j < 4; j++)
        s_t2[co * 64 + trow * 8 + xl0 + j] = lrelu_f(acc[k][j] + b);
    }
    __syncthreads();
    // phase 2: fused 1x1 (64 -> 3) epilogue
    if (tid < 192) {
      const int o = tid >> 6;     // wave-uniform
      const int pix = tid & 63;
      float sum = b_ep[o];
#pragma unroll
      for (int c = 0; c < 64; c++) sum += s_wep[o * 64 + c] * s_t2[c * 64 + pix];
      const int gy = y0 + (pix >> 3);
      const int gx = x0 + (pix & 7);
      out[((size_t)((size_t)n * 3 + o) * Ho + gy) * Wo + gx] = sum;
    }
  }
}

// BatchNorm (training-mode batch stats over N,H,W) + LeakyReLU, in place.
// One block per channel; N=2, H=W=16 -> 512 values = 2 per thread.
__global__ __launch_bounds__(256) void bn_lrelu_kernel(
    float* __restrict__ h, const float* __restrict__ gamma, const float* __restrict__ beta)
{
  const int c = blockIdx.x;            // 0..1023
  const int t = threadIdx.x;
  const size_t i0 = (size_t)c * 256 + t;
  const size_t i1 = (size_t)(1024 + c) * 256 + t;
  const float v0 = h[i0], v1 = h[i1];
  float s = v0 + v1;
  float q = v0 * v0 + v1 * v1;
  for (int o = 32; o > 0; o >>= 1) { s += __shfl_down(s, o); q += __shfl_down(q, o); }
  __shared__ float sh[8];
  __shared__ float param[2];
  const int wid = t >> 6, lane = t & 63;
  if (lane == 0) { sh[wid] = s; sh[4 + wid] = q; }
  __syncthreads();
  if (t == 0) {
    const float S = sh[0] + sh[1] + sh[2] + sh[3];
    const float Q = sh[4] + sh[5] + sh[6] + sh[7];
    const float mean = S * (1.f / 512.f);
    const float var = Q * (1.f / 512.f) - mean * mean;
    const float scale = gamma[c] / sqrtf(var + BN_EPS);
    param[0] = scale;
    param[1] = beta[c] - mean * scale;
  }
  __syncthreads();
  const float sc = param[0], sf = param[1];
  h[i0] = lrelu_f(v0 * sc + sf);
  h[i1] = lrelu_f(v1 * sc + sf);
}

extern "C" void kernel_launch(void* const* d_in, const int* in_sizes, int n_in,
                              void* d_out, int out_size, void* d_ws, size_t ws_size,
                              hipStream_t stream)
{
  (void)in_sizes; (void)n_in; (void)out_size; (void)ws_size;
  const float* x     = (const float*)d_in[0];
  const float* w_d0  = (const float*)d_in[1];
  const float* b_d0  = (const float*)d_in[2];
  const float* w_d1  = (const float*)d_in[3];
  const float* b_d1  = (const float*)d_in[4];
  const float* w_d2  = (const float*)d_in[5];
  const float* b_d2  = (const float*)d_in[6];
  const float* w_d3  = (const float*)d_in[7];
  const float* b_d3  = (const float*)d_in[8];
  const float* w_d4  = (const float*)d_in[9];
  const float* b_d4  = (const float*)d_in[10];
  const float* w_in  = (const float*)d_in[11];
  const float* b_in  = (const float*)d_in[12];
  const float* gamma = (const float*)d_in[13];
  const float* beta  = (const float*)d_in[14];
  const float* w_u0  = (const float*)d_in[15];
  const float* b_u0  = (const float*)d_in[16];
  const float* w_u1  = (const float*)d_in[17];
  const float* b_u1  = (const float*)d_in[18];
  const float* w_u2  = (const float*)d_in[19];
  const float* b_u2  = (const float*)d_in[20];
  const float* w_u3  = (const float*)d_in[21];
  const float* b_u3  = (const float*)d_in[22];
  const float* w_u4  = (const float*)d_in[23];
  const float* b_u4  = (const float*)d_in[24];
  const float* w_ep  = (const float*)d_in[25];
  const float* b_ep  = (const float*)d_in[26];

  // Ping-pong workspace slots: each <= 2*64*256*256 floats = 33,554,432 B. Total 64 MiB.
  float* S0 = (float*)d_ws;
  float* S1 = (float*)((char*)d_ws + (size_t)33554432);
  float* outp = (float*)d_out;

  const dim3 blk(256);
  // ---------------- encoder: conv+lrelu+down2 fused ----------------
  conv3_kernel<1, 4><<<dim3(32 * 32, 1, 2), blk, 0, stream>>>(x,  w_d0, b_d0, S0,   3, 512, 512,   64, 256, 256, 1, nullptr, nullptr);
  conv3_kernel<1, 4><<<dim3(16 * 16, 2, 2), blk, 0, stream>>>(S0, w_d1, b_d1, S1,  64, 256, 256,  128, 128, 128, 1, nullptr, nullptr);
  conv3_kernel<1, 4><<<dim3( 8 *  8, 4, 2), blk, 0, stream>>>(S1, w_d2, b_d2, S0, 128, 128, 128,  256,  64,  64, 1, nullptr, nullptr);
  conv3_kernel<1, 2><<<dim3( 4 *  4,16, 2), blk, 0, stream>>>(S0, w_d3, b_d3, S1, 256,  64,  64,  512,  32,  32, 1, nullptr, nullptr);
  conv3_kernel<1, 2><<<dim3( 2 *  2,32, 2), blk, 0, stream>>>(S1, w_d4, b_d4, S0, 512,  32,  32, 1024,  16,  16, 1, nullptr, nullptr);
  // ---------------- innermost conv (no act) + BN + lrelu ----------------
  conv3_kernel<0, 2><<<dim3( 2 *  2,32, 2), blk, 0, stream>>>(S0, w_in, b_in, S1, 1024, 16,  16, 1024,  16,  16, 0, nullptr, nullptr);
  bn_lrelu_kernel<<<dim3(1024), blk, 0, stream>>>(S1, gamma, beta);
  // ---------------- decoder: up2+conv+lrelu fused ----------------
  conv3_kernel<2, 2><<<dim3( 4 *  4,16, 2), blk, 0, stream>>>(S1, w_u0, b_u0, S0, 1024, 16,  16,  512,  32,  32, 1, nullptr, nullptr);
  conv3_kernel<2, 4><<<dim3( 8 *  8, 4, 2), blk, 0, stream>>>(S0, w_u1, b_u1, S1,  512, 32,  32,  256,  64,  64, 1, nullptr, nullptr);
  conv3_kernel<2, 4><<<dim3(16 * 16, 2, 2), blk, 0, stream>>>(S1, w_u2, b_u2, S0,  256, 64,  64,  128, 128, 128, 1, nullptr, nullptr);
  conv3_kernel<2, 4><<<dim3(32 * 32, 1, 2), blk, 0, stream>>>(S0, w_u3, b_u3, S1,  128, 128, 128,  64, 256, 256, 1, nullptr, nullptr);
  // ---------------- u4 conv + lrelu + fused 1x1 epilogue -> d_out ----------------
  conv3_kernel<3, 4><<<dim3(64 * 64, 1, 2), blk, 0, stream>>>(S1, w_u4, b_u4, outp, 64, 256, 256,  64, 512, 512, 1, w_ep, b_ep);
}

// Round 2
// 3618.595 us; speedup vs baseline: 1.4650x; 1.4650x over previous
//
#include <hip/hip_runtime.h>
#include <math.h>

#define LRELU_SLOPE 0.01f
#define BN_EPS 1e-5f
#define CI_CHUNK 4

__device__ __forceinline__ float lrelu_f(float v) { return v >= 0.f ? v : LRELU_SLOPE * v; }

// ---------------------------------------------------------------------------
// Encoder / plain conv kernel (MODE 0 = plain, MODE 1 = conv+lrelu+down2)
// Block 256. Output tile 8x8 px x (16*KCO) channels.
// Weights staged transposed: s_w[e*NCO + co] so thread reads its KCO weights
// as one vector load (b128 for KCO=4). MODE1 input staged de-interleaved
// (even cols [0..8], odd cols [10..17], pitch 20) for vector iv loads.
// ---------------------------------------------------------------------------
template <int MODE, int KCO>
__global__ __launch_bounds__(256) void conv3_kernel(
    const float* __restrict__ in, const float* __restrict__ wgt,
    const float* __restrict__ bias, float* __restrict__ out,
    int Cin, int Hin, int Win, int Cout, int Ho, int Wo, int apply_act)
{
  constexpr int NCO = 16 * KCO;
  constexpr int LOG = (KCO == 4) ? 6 : 5;
  constexpr int IH  = (MODE == 1) ? 17 : 10;
  constexpr int IP  = (MODE == 1) ? 20 : 12;
  __shared__ __align__(16) float s_in[CI_CHUNK * IH * IP];
  __shared__ __align__(16) float s_w[36 * NCO];

  const int tid  = threadIdx.x;
  const int tx   = tid & 15;
  const int ty   = tid >> 4;
  const int trow = ty >> 1;
  const int xl0  = (ty & 1) * 4;

  const int tilesX = Wo >> 3;
  const int x0   = (blockIdx.x % tilesX) * 8;
  const int y0   = (blockIdx.x / tilesX) * 8;
  const int cog0 = blockIdx.y * NCO;
  const int n    = blockIdx.z;

  const size_t HWin = (size_t)Hin * Win;
  const float* inN = in + (size_t)n * Cin * HWin;

  float acc[KCO][4];
#pragma unroll
  for (int a = 0; a < KCO; a++)
#pragma unroll
    for (int b = 0; b < 4; b++) acc[a][b] = 0.f;

  for (int ci0 = 0; ci0 < Cin; ci0 += CI_CHUNK) {
    const int chunk = (Cin - ci0 < CI_CHUNK) ? (Cin - ci0) : CI_CHUNK;
    __syncthreads();
    // ---- stage input tile ----
    const int tot = chunk * (IH * IH);
    for (int idx = tid; idx < tot; idx += 256) {
      const int ci  = idx / (IH * IH);
      const int rem = idx - ci * (IH * IH);
      const int r   = rem / IH;
      const int c   = rem - r * IH;
      float v = 0.f;
      if (MODE == 1) {
        const int gy = 2 * y0 - 1 + r;
        const int gx = 2 * x0 - 1 + c;
        if (gy >= 0 && gy < Hin && gx >= 0 && gx < Win)
          v = inN[(size_t)(ci0 + ci) * HWin + (size_t)gy * Win + gx];
        const int dst = (c & 1) ? (10 + (c >> 1)) : (c >> 1);  // de-interleave
        s_in[(ci * IH + r) * IP + dst] = v;
      } else {
        const int gy = y0 - 1 + r;
        const int gx = x0 - 1 + c;
        if (gy >= 0 && gy < Hin && gx >= 0 && gx < Win)
          v = inN[(size_t)(ci0 + ci) * HWin + (size_t)gy * Win + gx];
        s_in[(ci * IH + r) * IP + c] = v;
      }
    }
    // ---- stage weights transposed: s_w[e*NCO + co] (LDS-write coalesced) ----
    const int e9 = chunk * 9;
    const int wtot = e9 * NCO;
    for (int idx = tid; idx < wtot; idx += 256) {
      const int co = idx & (NCO - 1);
      const int e  = idx >> LOG;
      s_w[e * NCO + co] = wgt[(size_t)(cog0 + co) * Cin * 9 + (size_t)ci0 * 9 + e];
    }
    __syncthreads();

    auto body = [&](int ci) {
#pragma unroll
      for (int ky = 0; ky < 3; ky++) {
        if (MODE == 1) {
          const int base = (ci * 17 + 2 * trow + ky) * 20;
          const float4 e4 = *(const float4*)&s_in[base + xl0];
          const float  e5 = s_in[base + xl0 + 4];
          const float2 oa = *(const float2*)&s_in[base + 10 + xl0];
          const float2 ob = *(const float2*)&s_in[base + 12 + xl0];
          const float ev[5] = {e4.x, e4.y, e4.z, e4.w, e5};
          const float ov[4] = {oa.x, oa.y, ob.x, ob.y};
#pragma unroll
          for (int kx = 0; kx < 3; kx++) {
            const int e = ci * 9 + ky * 3 + kx;
            float wv[KCO];
            if constexpr (KCO == 4) {
              const float4 w4 = *(const float4*)&s_w[e * 64 + (tx << 2)];
              wv[0] = w4.x; wv[1] = w4.y; wv[2] = w4.z; wv[3] = w4.w;
            } else {
              const float2 w2 = *(const float2*)&s_w[e * 32 + (tx << 1)];
              wv[0] = w2.x; wv[1] = w2.y;
            }
#pragma unroll
            for (int j = 0; j < 4; j++) {
              const float xv = (kx == 0) ? ev[j] : ((kx == 1) ? ov[j] : ev[j + 1]);
#pragma unroll
              for (int k = 0; k < KCO; k++) acc[k][j] += wv[k] * xv;
            }
          }
        } else {
          const int base = (ci * 10 + trow + ky) * 12 + xl0;
          const float4 a4 = *(const float4*)&s_in[base];
          const float2 a2 = *(const float2*)&s_in[base + 4];
          const float iv[6] = {a4.x, a4.y, a4.z, a4.w, a2.x, a2.y};
#pragma unroll
          for (int kx = 0; kx < 3; kx++) {
            const int e = ci * 9 + ky * 3 + kx;
            float wv[KCO];
            if constexpr (KCO == 4) {
              const float4 w4 = *(const float4*)&s_w[e * 64 + (tx << 2)];
              wv[0] = w4.x; wv[1] = w4.y; wv[2] = w4.z; wv[3] = w4.w;
            } else {
              const float2 w2 = *(const float2*)&s_w[e * 32 + (tx << 1)];
              wv[0] = w2.x; wv[1] = w2.y;
            }
#pragma unroll
            for (int j = 0; j < 4; j++) {
              const float xv = iv[j + kx];
#pragma unroll
              for (int k = 0; k < KCO; k++) acc[k][j] += wv[k] * xv;
            }
          }
        }
      }
    };
    if (chunk == CI_CHUNK) {
#pragma unroll
      for (int ci = 0; ci < CI_CHUNK; ci++) body(ci);
    } else {
      for (int ci = 0; ci < chunk; ci++) body(ci);  // only d0 (Cin=3)
    }
  }

#pragma unroll
  for (int k = 0; k < KCO; k++) {
    const int co = cog0 + tx * KCO + k;
    const float b = bias[co];
    float4 v;
    v.x = acc[k][0] + b; v.y = acc[k][1] + b; v.z = acc[k][2] + b; v.w = acc[k][3] + b;
    if (apply_act) { v.x = lrelu_f(v.x); v.y = lrelu_f(v.y); v.z = lrelu_f(v.z); v.w = lrelu_f(v.w); }
    float* op = out + ((size_t)((size_t)n * Cout + co) * Ho + (y0 + trow)) * Wo + x0 + xl0;
    *reinterpret_cast<float4*>(op) = v;
  }
}

// ---------------------------------------------------------------------------
// Decoder kernel: zero-insert up2 + conv3x3 + lrelu, parity-decomposed.
// Each thread computes NQ x NQ output "quads" (quad = 2x2 px, one pixel per
// parity class). Per quad per co: exactly 9 taps (1+2+2+4) -- wave-uniform,
// 4x less work than dense conv over the zero-inserted input.
// EPI=true (u4): fuse the 1x1 (64->3) epilogue via __shfl_xor reduction over
// the 16 co-lanes (no LDS round trip).
// Hin/Win are the SMALL (pre-upsample) dims; Ho=2*Hin, Wo=2*Win.
// ---------------------------------------------------------------------------
template <int NQ, int KCO, bool EPI>
__global__ __launch_bounds__(256) void up_conv_kernel(
    const float* __restrict__ in, const float* __restrict__ wgt,
    const float* __restrict__ bias, float* __restrict__ out,
    int Cin, int Hin, int Win, int Cout, int Ho, int Wo,
    const float* __restrict__ w_ep, const float* __restrict__ b_ep)
{
  constexpr int NCO = 16 * KCO;
  constexpr int LOG = (KCO == 4) ? 6 : 5;
  constexpr int TQ = 2 * NQ;       // px per thread per dim
  constexpr int T  = 4 * TQ;       // output tile dim
  constexpr int IR = 4 * NQ + 1;   // staged input rows/cols per ci
  constexpr int PR = IR + 1;       // pitch
  __shared__ __align__(16) float s_in[CI_CHUNK * IR * PR];
  __shared__ __align__(16) float s_w[36 * NCO];

  const int tid = threadIdx.x;
  const int tx  = tid & 15;
  const int ty  = tid >> 4;
  const int Qy  = ty >> 2;
  const int Qx  = ty & 3;

  const int tilesX = Wo / T;
  const int x0   = (blockIdx.x % tilesX) * T;
  const int y0   = (blockIdx.x / tilesX) * T;
  const int cog0 = blockIdx.y * NCO;
  const int n    = blockIdx.z;
  const int r0 = y0 >> 1;
  const int c0 = x0 >> 1;

  const size_t HWin = (size_t)Hin * Win;
  const float* inN = in + (size_t)n * Cin * HWin;

  float wep[3][KCO];
  if (EPI) {
#pragma unroll
    for (int o = 0; o < 3; o++)
#pragma unroll
      for (int k = 0; k < KCO; k++) wep[o][k] = w_ep[o * 64 + tx * KCO + k];
  }

  float acc[KCO][TQ][TQ];
#pragma unroll
  for (int k = 0; k < KCO; k++)
#pragma unroll
    for (int i = 0; i < TQ; i++)
#pragma unroll
      for (int j = 0; j < TQ; j++) acc[k][i][j] = 0.f;

  for (int ci0 = 0; ci0 < Cin; ci0 += CI_CHUNK) {
    __syncthreads();
    // ---- stage raw (non-zero-inserted) input tile, zero-pad hi edge ----
    const int tot = CI_CHUNK * (IR * IR);
    for (int idx = tid; idx < tot; idx += 256) {
      const int ci  = idx / (IR * IR);
      const int rem = idx - ci * (IR * IR);
      const int r   = rem / IR;
      const int c   = rem - r * IR;
      const int gy = r0 + r, gx = c0 + c;
      float v = 0.f;
      if (gy < Hin && gx < Win)
        v = inN[(size_t)(ci0 + ci) * HWin + (size_t)gy * Win + gx];
      s_in[(ci * IR + r) * PR + c] = v;
    }
    // ---- stage weights transposed ----
    const int wtot = CI_CHUNK * 9 * NCO;
    for (int idx = tid; idx < wtot; idx += 256) {
      const int co = idx & (NCO - 1);
      const int e  = idx >> LOG;
      s_w[e * NCO + co] = wgt[(size_t)(cog0 + co) * Cin * 9 + (size_t)ci0 * 9 + e];
    }
    __syncthreads();

#pragma unroll
    for (int ci = 0; ci < CI_CHUNK; ci++) {
      float iv[NQ + 1][NQ + 1];
#pragma unroll
      for (int dr = 0; dr <= NQ; dr++)
#pragma unroll
        for (int dc = 0; dc <= NQ; dc++)
          iv[dr][dc] = s_in[(ci * IR + NQ * Qy + dr) * PR + NQ * Qx + dc];
#pragma unroll
      for (int t = 0; t < 9; t++) {
        const int ky = t / 3, kx = t % 3;
        float wv[KCO];
        if constexpr (KCO == 4) {
          const float4 w4 = *(const float4*)&s_w[(ci * 9 + t) * 64 + (tx << 2)];
          wv[0] = w4.x; wv[1] = w4.y; wv[2] = w4.z; wv[3] = w4.w;
        } else {
          const float2 w2 = *(const float2*)&s_w[(ci * 9 + t) * 32 + (tx << 1)];
          wv[0] = w2.x; wv[1] = w2.y;
        }
        const int pr  = (ky == 1) ? 0 : 1;   // output row parity this tap feeds
        const int drr = (ky == 2) ? 1 : 0;   // input row offset
        const int pc  = (kx == 1) ? 0 : 1;
        const int dcc = (kx == 2) ? 1 : 0;
#pragma unroll
        for (int a = 0; a < NQ; a++)
#pragma unroll
          for (int b = 0; b < NQ; b++) {
            const float xv = iv[a + drr][b + dcc];
#pragma unroll
            for (int k = 0; k < KCO; k++)
              acc[k][2 * a + pr][2 * b + pc] += wv[k] * xv;
          }
      }
    }
  }

  if (!EPI) {
#pragma unroll
    for (int k = 0; k < KCO; k++) {
      const int co = cog0 + tx * KCO + k;
      const float bv = bias[co];
#pragma unroll
      for (int i = 0; i < TQ; i++) {
        const int y = y0 + TQ * Qy + i;
        float* op = out + ((size_t)((size_t)n * Cout + co) * Ho + y) * Wo + x0 + TQ * Qx;
        if constexpr (NQ == 2) {
          float4 v;
          v.x = lrelu_f(acc[k][i][0] + bv); v.y = lrelu_f(acc[k][i][1] + bv);
          v.z = lrelu_f(acc[k][i][2] + bv); v.w = lrelu_f(acc[k][i][3] + bv);
          *reinterpret_cast<float4*>(op) = v;
        } else {
          float2 v;
          v.x = lrelu_f(acc[k][i][0] + bv); v.y = lrelu_f(acc[k][i][1] + bv);
          *reinterpret_cast<float2*>(op) = v;
        }
      }
    }
  } else {
    // fused 1x1 (64 -> 3): per-pixel partial dot over this thread's KCO cos,
    // then butterfly-reduce across the 16 co-lanes (tx = lane&15).
    const float bv[KCO] = {bias[tx * KCO + 0], bias[tx * KCO + 1],
                           bias[tx * KCO + 2], bias[tx * KCO + 3]};
#pragma unroll
    for (int i = 0; i < TQ; i++)
#pragma unroll
      for (int j = 0; j < TQ; j++) {
        float h[KCO];
#pragma unroll
        for (int k = 0; k < KCO; k++) h[k] = lrelu_f(acc[k][i][j] + bv[k]);
        float s0 = 0.f, s1 = 0.f, s2 = 0.f;
#pragma unroll
        for (int k = 0; k < KCO; k++) {
          s0 += wep[0][k] * h[k]; s1 += wep[1][k] * h[k]; s2 += wep[2][k] * h[k];
        }
#pragma unroll
        for (int m = 1; m < 16; m <<= 1) {
          s0 += __shfl_xor(s0, m); s1 += __shfl_xor(s1, m); s2 += __shfl_xor(s2, m);
        }
        if (tx < 3) {
          const float sv = (tx == 0) ? s0 : ((tx == 1) ? s1 : s2);
          const int y = y0 + TQ * Qy + i;
          const int x = x0 + TQ * Qx + j;
          out[((size_t)((size_t)n * 3 + tx) * Ho + y) * Wo + x] = sv + b_ep[tx];
        }
      }
  }
}

// BatchNorm (batch stats over N,H,W) + LeakyReLU, in place. 1 block/channel.
__global__ __launch_bounds__(256) void bn_lrelu_kernel(
    float* __restrict__ h, const float* __restrict__ gamma, const float* __restrict__ beta)
{
  const int c = blockIdx.x;
  const int t = threadIdx.x;
  const size_t i0 = (size_t)c * 256 + t;
  const size_t i1 = (size_t)(1024 + c) * 256 + t;
  const float v0 = h[i0], v1 = h[i1];
  float s = v0 + v1;
  float q = v0 * v0 + v1 * v1;
  for (int o = 32; o > 0; o >>= 1) { s += __shfl_down(s, o); q += __shfl_down(q, o); }
  __shared__ float sh[8];
  __shared__ float param[2];
  const int wid = t >> 6, lane = t & 63;
  if (lane == 0) { sh[wid] = s; sh[4 + wid] = q; }
  __syncthreads();
  if (t == 0) {
    const float S = sh[0] + sh[1] + sh[2] + sh[3];
    const float Q = sh[4] + sh[5] + sh[6] + sh[7];
    const float mean = S * (1.f / 512.f);
    const float var = Q * (1.f / 512.f) - mean * mean;
    const float scale = gamma[c] / sqrtf(var + BN_EPS);
    param[0] = scale;
    param[1] = beta[c] - mean * scale;
  }
  __syncthreads();
  const float sc = param[0], sf = param[1];
  h[i0] = lrelu_f(v0 * sc + sf);
  h[i1] = lrelu_f(v1 * sc + sf);
}

extern "C" void kernel_launch(void* const* d_in, const int* in_sizes, int n_in,
                              void* d_out, int out_size, void* d_ws, size_t ws_size,
                              hipStream_t stream)
{
  (void)in_sizes; (void)n_in; (void)out_size; (void)ws_size;
  const float* x     = (const float*)d_in[0];
  const float* w_d0  = (const float*)d_in[1];
  const float* b_d0  = (const float*)d_in[2];
  const float* w_d1  = (const float*)d_in[3];
  const float* b_d1  = (const float*)d_in[4];
  const float* w_d2  = (const float*)d_in[5];
  const float* b_d2  = (const float*)d_in[6];
  const float* w_d3  = (const float*)d_in[7];
  const float* b_d3  = (const float*)d_in[8];
  const float* w_d4  = (const float*)d_in[9];
  const float* b_d4  = (const float*)d_in[10];
  const float* w_in  = (const float*)d_in[11];
  const float* b_in  = (const float*)d_in[12];
  const float* gamma = (const float*)d_in[13];
  const float* beta  = (const float*)d_in[14];
  const float* w_u0  = (const float*)d_in[15];
  const float* b_u0  = (const float*)d_in[16];
  const float* w_u1  = (const float*)d_in[17];
  const float* b_u1  = (const float*)d_in[18];
  const float* w_u2  = (const float*)d_in[19];
  const float* b_u2  = (const float*)d_in[20];
  const float* w_u3  = (const float*)d_in[21];
  const float* b_u3  = (const float*)d_in[22];
  const float* w_u4  = (const float*)d_in[23];
  const float* b_u4  = (const float*)d_in[24];
  const float* w_ep  = (const float*)d_in[25];
  const float* b_ep  = (const float*)d_in[26];

  float* S0 = (float*)d_ws;
  float* S1 = (float*)((char*)d_ws + (size_t)33554432);
  float* outp = (float*)d_out;

  const dim3 blk(256);
  // encoder: conv+lrelu+down2 fused
  conv3_kernel<1, 4><<<dim3(1024, 1, 2), blk, 0, stream>>>(x,  w_d0, b_d0, S0,   3, 512, 512,   64, 256, 256, 1);
  conv3_kernel<1, 4><<<dim3( 256, 2, 2), blk, 0, stream>>>(S0, w_d1, b_d1, S1,  64, 256, 256,  128, 128, 128, 1);
  conv3_kernel<1, 4><<<dim3(  64, 4, 2), blk, 0, stream>>>(S1, w_d2, b_d2, S0, 128, 128, 128,  256,  64,  64, 1);
  conv3_kernel<1, 4><<<dim3(  16, 8, 2), blk, 0, stream>>>(S0, w_d3, b_d3, S1, 256,  64,  64,  512,  32,  32, 1);
  conv3_kernel<1, 2><<<dim3(   4,32, 2), blk, 0, stream>>>(S1, w_d4, b_d4, S0, 512,  32,  32, 1024,  16,  16, 1);
  // innermost conv (no act) + BN + lrelu
  conv3_kernel<0, 2><<<dim3(   4,32, 2), blk, 0, stream>>>(S0, w_in, b_in, S1, 1024, 16,  16, 1024,  16,  16, 0);
  bn_lrelu_kernel<<<dim3(1024), blk, 0, stream>>>(S1, gamma, beta);
  // decoder: parity-decomposed up2+conv+lrelu
  up_conv_kernel<1, 4, false><<<dim3(  16, 8, 2), blk, 0, stream>>>(S1, w_u0, b_u0, S0, 1024, 16,  16,  512,  32,  32, nullptr, nullptr);
  up_conv_kernel<1, 4, false><<<dim3(  64, 4, 2), blk, 0, stream>>>(S0, w_u1, b_u1, S1,  512, 32,  32,  256,  64,  64, nullptr, nullptr);
  up_conv_kernel<2, 4, false><<<dim3(  64, 2, 2), blk, 0, stream>>>(S1, w_u2, b_u2, S0,  256, 64,  64,  128, 128, 128, nullptr, nullptr);
  up_conv_kernel<2, 4, false><<<dim3( 256, 1, 2), blk, 0, stream>>>(S0, w_u3, b_u3, S1,  128, 128, 128,  64, 256, 256, nullptr, nullptr);
  // u4 + fused 1x1 epilogue -> d_out
  up_conv_kernel<2, 4, true ><<<dim3(1024, 1, 2), blk, 0, stream>>>(S1, w_u4, b_u4, outp, 64, 256, 256,  64, 512, 512, w_ep, b_ep);
}

// Round 3
// 3157.573 us; speedup vs baseline: 1.6789x; 1.1460x over previous
//
#include <hip/hip_runtime.h>
#include <math.h>

#define LRELU_SLOPE 0.01f
#define BN_EPS 1e-5f

__device__ __forceinline__ float lrelu_f(float v) { return v >= 0.f ? v : LRELU_SLOPE * v; }

// ---------------------------------------------------------------------------
// Encoder / plain conv kernel (MODE 0 = plain, MODE 1 = conv+lrelu+down2).
// Block 256, output tile 8x8 px x 64 co. K-split: blockIdx.y = seg*cogY+cog;
// each segment covers segCi input channels; PARTIAL writes raw acc to
// out + seg*seg_stride (reduce kernel applies bias+act).
// ---------------------------------------------------------------------------
template <int MODE, int KCO, int CC, bool PARTIAL>
__global__ __launch_bounds__(256, 4) void conv3_kernel(
    const float* __restrict__ in, const float* __restrict__ wgt,
    const float* __restrict__ bias, float* __restrict__ out,
    int Cin, int Hin, int Win, int Cout, int Ho, int Wo, int apply_act,
    int segCi, int cogY, size_t seg_stride)
{
  constexpr int NCO = 16 * KCO;
  constexpr int LOG = (KCO == 4) ? 6 : 5;
  constexpr int IH  = (MODE == 1) ? 17 : 10;
  constexpr int IP  = (MODE == 1) ? 20 : 12;
  __shared__ __align__(16) float s_in[CC * IH * IP];
  __shared__ __align__(16) float s_w[CC * 9 * NCO];

  const int tid  = threadIdx.x;
  const int tx   = tid & 15;
  const int ty   = tid >> 4;
  const int trow = ty >> 1;
  const int xl0  = (ty & 1) * 4;

  const int tilesX = Wo >> 3;
  const int x0   = (blockIdx.x % tilesX) * 8;
  const int y0   = (blockIdx.x / tilesX) * 8;
  const int cog0 = (blockIdx.y % cogY) * NCO;
  const int seg  = blockIdx.y / cogY;
  const int ci_begin = seg * segCi;
  const int n    = blockIdx.z;
  if (PARTIAL) out += (size_t)seg * seg_stride;

  const size_t HWin = (size_t)Hin * Win;
  const float* inN = in + (size_t)n * Cin * HWin;

  float acc[KCO][4];
#pragma unroll
  for (int a = 0; a < KCO; a++)
#pragma unroll
    for (int b = 0; b < 4; b++) acc[a][b] = 0.f;

  for (int ci0 = 0; ci0 < segCi; ci0 += CC) {
    const int chunk = (segCi - ci0 < CC) ? (segCi - ci0) : CC;
    __syncthreads();
    // ---- stage input tile ----
    const int tot = chunk * (IH * IH);
    for (int idx = tid; idx < tot; idx += 256) {
      const int ci  = idx / (IH * IH);
      const int rem = idx - ci * (IH * IH);
      const int r   = rem / IH;
      const int c   = rem - r * IH;
      float v = 0.f;
      const int gci = ci_begin + ci0 + ci;
      if (MODE == 1) {
        const int gy = 2 * y0 - 1 + r;
        const int gx = 2 * x0 - 1 + c;
        if (gy >= 0 && gy < Hin && gx >= 0 && gx < Win)
          v = inN[(size_t)gci * HWin + (size_t)gy * Win + gx];
        const int dst = (c & 1) ? (10 + (c >> 1)) : (c >> 1);  // de-interleave
        s_in[(ci * IH + r) * IP + dst] = v;
      } else {
        const int gy = y0 - 1 + r;
        const int gx = x0 - 1 + c;
        if (gy >= 0 && gy < Hin && gx >= 0 && gx < Win)
          v = inN[(size_t)gci * HWin + (size_t)gy * Win + gx];
        s_in[(ci * IH + r) * IP + c] = v;
      }
    }
    // ---- stage weights transposed: s_w[e*NCO + co] ----
    const int e9 = chunk * 9;
    const int wtot = e9 * NCO;
    for (int idx = tid; idx < wtot; idx += 256) {
      const int co = idx & (NCO - 1);
      const int e  = idx >> LOG;
      s_w[e * NCO + co] = wgt[(size_t)(cog0 + co) * Cin * 9 + (size_t)(ci_begin + ci0) * 9 + e];
    }
    __syncthreads();

    auto body = [&](int ci) {
#pragma unroll
      for (int ky = 0; ky < 3; ky++) {
        if (MODE == 1) {
          const int base = (ci * IH + 2 * trow + ky) * IP;
          const float4 e4 = *(const float4*)&s_in[base + xl0];
          const float  e5 = s_in[base + xl0 + 4];
          const float2 oa = *(const float2*)&s_in[base + 10 + xl0];
          const float2 ob = *(const float2*)&s_in[base + 12 + xl0];
          const float ev[5] = {e4.x, e4.y, e4.z, e4.w, e5};
          const float ov[4] = {oa.x, oa.y, ob.x, ob.y};
#pragma unroll
          for (int kx = 0; kx < 3; kx++) {
            const int e = ci * 9 + ky * 3 + kx;
            float wv[KCO];
            if constexpr (KCO == 4) {
              const float4 w4 = *(const float4*)&s_w[e * 64 + (tx << 2)];
              wv[0] = w4.x; wv[1] = w4.y; wv[2] = w4.z; wv[3] = w4.w;
            } else {
              const float2 w2 = *(const float2*)&s_w[e * 32 + (tx << 1)];
              wv[0] = w2.x; wv[1] = w2.y;
            }
#pragma unroll
            for (int j = 0; j < 4; j++) {
              const float xv = (kx == 0) ? ev[j] : ((kx == 1) ? ov[j] : ev[j + 1]);
#pragma unroll
              for (int k = 0; k < KCO; k++) acc[k][j] += wv[k] * xv;
            }
          }
        } else {
          const int base = (ci * IH + trow + ky) * IP + xl0;
          const float4 a4 = *(const float4*)&s_in[base];
          const float2 a2 = *(const float2*)&s_in[base + 4];
          const float iv[6] = {a4.x, a4.y, a4.z, a4.w, a2.x, a2.y};
#pragma unroll
          for (int kx = 0; kx < 3; kx++) {
            const int e = ci * 9 + ky * 3 + kx;
            float wv[KCO];
            if constexpr (KCO == 4) {
              const float4 w4 = *(const float4*)&s_w[e * 64 + (tx << 2)];
              wv[0] = w4.x; wv[1] = w4.y; wv[2] = w4.z; wv[3] = w4.w;
            } else {
              const float2 w2 = *(const float2*)&s_w[e * 32 + (tx << 1)];
              wv[0] = w2.x; wv[1] = w2.y;
            }
#pragma unroll
            for (int j = 0; j < 4; j++) {
              const float xv = iv[j + kx];
#pragma unroll
              for (int k = 0; k < KCO; k++) acc[k][j] += wv[k] * xv;
            }
          }
        }
      }
    };
    if (chunk == CC) {
#pragma unroll
      for (int ci = 0; ci < CC; ci++) body(ci);
    } else {
      for (int ci = 0; ci < chunk; ci++) body(ci);  // only d0 (Cin=3)
    }
  }

#pragma unroll
  for (int k = 0; k < KCO; k++) {
    const int co = cog0 + tx * KCO + k;
    float* op = out + ((size_t)((size_t)n * Cout + co) * Ho + (y0 + trow)) * Wo + x0 + xl0;
    float4 v;
    if constexpr (PARTIAL) {
      v.x = acc[k][0]; v.y = acc[k][1]; v.z = acc[k][2]; v.w = acc[k][3];
    } else {
      const float b = bias[co];
      v.x = acc[k][0] + b; v.y = acc[k][1] + b; v.z = acc[k][2] + b; v.w = acc[k][3] + b;
      if (apply_act) { v.x = lrelu_f(v.x); v.y = lrelu_f(v.y); v.z = lrelu_f(v.z); v.w = lrelu_f(v.w); }
    }
    *reinterpret_cast<float4*>(op) = v;
  }
}

// ---------------------------------------------------------------------------
// Decoder kernel: zero-insert up2 + conv3x3 (+lrelu), parity-decomposed.
// Per-thread NQ x NQ output quads (quad = 2x2 px, one per parity class):
// exactly 9 taps per quad per co. K-split via segCi/cogY/seg_stride like
// conv3_kernel. EPI fuses the 1x1 (64->3) epilogue via __shfl_xor.
// ---------------------------------------------------------------------------
template <int NQ, int KCO, int CC, bool EPI, bool PARTIAL>
__global__ __launch_bounds__(256, 4) void up_conv_kernel(
    const float* __restrict__ in, const float* __restrict__ wgt,
    const float* __restrict__ bias, float* __restrict__ out,
    int Cin, int Hin, int Win, int Cout, int Ho, int Wo,
    int segCi, int cogY, size_t seg_stride,
    const float* __restrict__ w_ep, const float* __restrict__ b_ep)
{
  constexpr int NCO = 16 * KCO;
  constexpr int LOG = (KCO == 4) ? 6 : 5;
  constexpr int TQ = 2 * NQ;
  constexpr int T  = 4 * TQ;
  constexpr int IR = 4 * NQ + 1;
  constexpr int PR = IR + 1;
  __shared__ __align__(16) float s_in[CC * IR * PR];
  __shared__ __align__(16) float s_w[CC * 9 * NCO];

  const int tid = threadIdx.x;
  const int tx  = tid & 15;
  const int ty  = tid >> 4;
  const int Qy  = ty >> 2;
  const int Qx  = ty & 3;

  const int tilesX = Wo / T;
  const int x0   = (blockIdx.x % tilesX) * T;
  const int y0   = (blockIdx.x / tilesX) * T;
  const int cog0 = (blockIdx.y % cogY) * NCO;
  const int seg  = blockIdx.y / cogY;
  const int ci_begin = seg * segCi;
  const int n    = blockIdx.z;
  if (PARTIAL) out += (size_t)seg * seg_stride;
  const int r0 = y0 >> 1;
  const int c0 = x0 >> 1;

  const size_t HWin = (size_t)Hin * Win;
  const float* inN = in + (size_t)n * Cin * HWin;

  float wep[3][KCO];
  if (EPI) {
#pragma unroll
    for (int o = 0; o < 3; o++)
#pragma unroll
      for (int k = 0; k < KCO; k++) wep[o][k] = w_ep[o * 64 + tx * KCO + k];
  }

  float acc[KCO][TQ][TQ];
#pragma unroll
  for (int k = 0; k < KCO; k++)
#pragma unroll
    for (int i = 0; i < TQ; i++)
#pragma unroll
      for (int j = 0; j < TQ; j++) acc[k][i][j] = 0.f;

  for (int ci0 = 0; ci0 < segCi; ci0 += CC) {
    __syncthreads();
    // ---- stage raw (non-zero-inserted) input tile, zero-pad hi edge ----
    const int tot = CC * (IR * IR);
    for (int idx = tid; idx < tot; idx += 256) {
      const int ci  = idx / (IR * IR);
      const int rem = idx - ci * (IR * IR);
      const int r   = rem / IR;
      const int c   = rem - r * IR;
      const int gy = r0 + r, gx = c0 + c;
      float v = 0.f;
      if (gy < Hin && gx < Win)
        v = inN[(size_t)(ci_begin + ci0 + ci) * HWin + (size_t)gy * Win + gx];
      s_in[(ci * IR + r) * PR + c] = v;
    }
    // ---- stage weights transposed ----
    const int wtot = CC * 9 * NCO;
    for (int idx = tid; idx < wtot; idx += 256) {
      const int co = idx & (NCO - 1);
      const int e  = idx >> LOG;
      s_w[e * NCO + co] = wgt[(size_t)(cog0 + co) * Cin * 9 + (size_t)(ci_begin + ci0) * 9 + e];
    }
    __syncthreads();

#pragma unroll
    for (int ci = 0; ci < CC; ci++) {
      float iv[NQ + 1][NQ + 1];
#pragma unroll
      for (int dr = 0; dr <= NQ; dr++)
#pragma unroll
        for (int dc = 0; dc <= NQ; dc++)
          iv[dr][dc] = s_in[(ci * IR + NQ * Qy + dr) * PR + NQ * Qx + dc];
#pragma unroll
      for (int t = 0; t < 9; t++) {
        const int ky = t / 3, kx = t % 3;
        float wv[KCO];
        if constexpr (KCO == 4) {
          const float4 w4 = *(const float4*)&s_w[(ci * 9 + t) * 64 + (tx << 2)];
          wv[0] = w4.x; wv[1] = w4.y; wv[2] = w4.z; wv[3] = w4.w;
        } else {
          const float2 w2 = *(const float2*)&s_w[(ci * 9 + t) * 32 + (tx << 1)];
          wv[0] = w2.x; wv[1] = w2.y;
        }
        const int pr  = (ky == 1) ? 0 : 1;
        const int drr = (ky == 2) ? 1 : 0;
        const int pc  = (kx == 1) ? 0 : 1;
        const int dcc = (kx == 2) ? 1 : 0;
#pragma unroll
        for (int a = 0; a < NQ; a++)
#pragma unroll
          for (int b = 0; b < NQ; b++) {
            const float xv = iv[a + drr][b + dcc];
#pragma unroll
            for (int k = 0; k < KCO; k++)
              acc[k][2 * a + pr][2 * b + pc] += wv[k] * xv;
          }
      }
    }
  }

  if (!EPI) {
#pragma unroll
    for (int k = 0; k < KCO; k++) {
      const int co = cog0 + tx * KCO + k;
      const float bv = PARTIAL ? 0.f : bias[co];
#pragma unroll
      for (int i = 0; i < TQ; i++) {
        const int y = y0 + TQ * Qy + i;
        float* op = out + ((size_t)((size_t)n * Cout + co) * Ho + y) * Wo + x0 + TQ * Qx;
        if constexpr (NQ == 2) {
          float4 v;
          if constexpr (PARTIAL) {
            v.x = acc[k][i][0]; v.y = acc[k][i][1]; v.z = acc[k][i][2]; v.w = acc[k][i][3];
          } else {
            v.x = lrelu_f(acc[k][i][0] + bv); v.y = lrelu_f(acc[k][i][1] + bv);
            v.z = lrelu_f(acc[k][i][2] + bv); v.w = lrelu_f(acc[k][i][3] + bv);
          }
          *reinterpret_cast<float4*>(op) = v;
        } else {
          float2 v;
          if constexpr (PARTIAL) {
            v.x = acc[k][i][0]; v.y = acc[k][i][1];
          } else {
            v.x = lrelu_f(acc[k][i][0] + bv); v.y = lrelu_f(acc[k][i][1] + bv);
          }
          *reinterpret_cast<float2*>(op) = v;
        }
      }
    }
  } else {
    const float bv[KCO] = {bias[tx * KCO + 0], bias[tx * KCO + 1],
                           bias[tx * KCO + 2], bias[tx * KCO + 3]};
#pragma unroll
    for (int i = 0; i < TQ; i++)
#pragma unroll
      for (int j = 0; j < TQ; j++) {
        float h[KCO];
#pragma unroll
        for (int k = 0; k < KCO; k++) h[k] = lrelu_f(acc[k][i][j] + bv[k]);
        float s0 = 0.f, s1 = 0.f, s2 = 0.f;
#pragma unroll
        for (int k = 0; k < KCO; k++) {
          s0 += wep[0][k] * h[k]; s1 += wep[1][k] * h[k]; s2 += wep[2][k] * h[k];
        }
#pragma unroll
        for (int m = 1; m < 16; m <<= 1) {
          s0 += __shfl_xor(s0, m); s1 += __shfl_xor(s1, m); s2 += __shfl_xor(s2, m);
        }
        if (tx < 3) {
          const float sv = (tx == 0) ? s0 : ((tx == 1) ? s1 : s2);
          const int y = y0 + TQ * Qy + i;
          const int x = x0 + TQ * Qx + j;
          out[((size_t)((size_t)n * 3 + tx) * Ho + y) * Wo + x] = sv + b_ep[tx];
        }
      }
  }
}

// ---------------------------------------------------------------------------
// Sum K-split partials + bias (+lrelu), vectorized float4.
// Layout per segment: [n][co][h][w]; HW divisible by 4.
// ---------------------------------------------------------------------------
__global__ __launch_bounds__(256) void reduce_bias_act_kernel(
    float* __restrict__ dst, const float* __restrict__ part,
    const float* __restrict__ bias, int total4, int HW, int Cout,
    int S, int seg_stride4, int act)
{
  const int i = blockIdx.x * 256 + threadIdx.x;
  if (i >= total4) return;
  const float4* p = (const float4*)part;
  float4 s = p[i];
  for (int k = 1; k < S; k++) {
    const float4 v = p[i + (size_t)k * seg_stride4];
    s.x += v.x; s.y += v.y; s.z += v.z; s.w += v.w;
  }
  const int co = ((i << 2) / HW) % Cout;
  const float b = bias[co];
  s.x += b; s.y += b; s.z += b; s.w += b;
  if (act) { s.x = lrelu_f(s.x); s.y = lrelu_f(s.y); s.z = lrelu_f(s.z); s.w = lrelu_f(s.w); }
  ((float4*)dst)[i] = s;
}

// BatchNorm (batch stats over N,H,W) + LeakyReLU, in place. 1 block/channel.
__global__ __launch_bounds__(256) void bn_lrelu_kernel(
    float* __restrict__ h, const float* __restrict__ gamma, const float* __restrict__ beta)
{
  const int c = blockIdx.x;
  const int t = threadIdx.x;
  const size_t i0 = (size_t)c * 256 + t;
  const size_t i1 = (size_t)(1024 + c) * 256 + t;
  const float v0 = h[i0], v1 = h[i1];
  float s = v0 + v1;
  float q = v0 * v0 + v1 * v1;
  for (int o = 32; o > 0; o >>= 1) { s += __shfl_down(s, o); q += __shfl_down(q, o); }
  __shared__ float sh[8];
  __shared__ float param[2];
  const int wid = t >> 6, lane = t & 63;
  if (lane == 0) { sh[wid] = s; sh[4 + wid] = q; }
  __syncthreads();
  if (t == 0) {
    const float S = sh[0] + sh[1] + sh[2] + sh[3];
    const float Q = sh[4] + sh[5] + sh[6] + sh[7];
    const float mean = S * (1.f / 512.f);
    const float var = Q * (1.f / 512.f) - mean * mean;
    const float scale = gamma[c] / sqrtf(var + BN_EPS);
    param[0] = scale;
    param[1] = beta[c] - mean * scale;
  }
  __syncthreads();
  const float sc = param[0], sf = param[1];
  h[i0] = lrelu_f(v0 * sc + sf);
  h[i1] = lrelu_f(v1 * sc + sf);
}

extern "C" void kernel_launch(void* const* d_in, const int* in_sizes, int n_in,
                              void* d_out, int out_size, void* d_ws, size_t ws_size,
                              hipStream_t stream)
{
  (void)in_sizes; (void)n_in; (void)out_size; (void)ws_size;
  const float* x     = (const float*)d_in[0];
  const float* w_d0  = (const float*)d_in[1];
  const float* b_d0  = (const float*)d_in[2];
  const float* w_d1  = (const float*)d_in[3];
  const float* b_d1  = (const float*)d_in[4];
  const float* w_d2  = (const float*)d_in[5];
  const float* b_d2  = (const float*)d_in[6];
  const float* w_d3  = (const float*)d_in[7];
  const float* b_d3  = (const float*)d_in[8];
  const float* w_d4  = (const float*)d_in[9];
  const float* b_d4  = (const float*)d_in[10];
  const float* w_in  = (const float*)d_in[11];
  const float* b_in  = (const float*)d_in[12];
  const float* gamma = (const float*)d_in[13];
  const float* beta  = (const float*)d_in[14];
  const float* w_u0  = (const float*)d_in[15];
  const float* b_u0  = (const float*)d_in[16];
  const float* w_u1  = (const float*)d_in[17];
  const float* b_u1  = (const float*)d_in[18];
  const float* w_u2  = (const float*)d_in[19];
  const float* b_u2  = (const float*)d_in[20];
  const float* w_u3  = (const float*)d_in[21];
  const float* b_u3  = (const float*)d_in[22];
  const float* w_u4  = (const float*)d_in[23];
  const float* b_u4  = (const float*)d_in[24];
  const float* w_ep  = (const float*)d_in[25];
  const float* b_ep  = (const float*)d_in[26];

  // ws layout: two 32 MiB ping-pong slots; K-split partials (<=16.8 MB) live
  // in the DESTINATION slot at +12 MiB (dst region itself is <=8.4 MB).
  float* S0 = (float*)d_ws;
  float* S1 = (float*)((char*)d_ws + (size_t)33554432);
  float* P0 = S0 + 3145728;   // S0 + 12 MiB
  float* P1 = S1 + 3145728;   // S1 + 12 MiB
  float* outp = (float*)d_out;

  const dim3 blk(256);
  // -------- encoder (conv+lrelu+down2 fused) --------
  conv3_kernel<1, 4, 4, false><<<dim3(1024, 1, 2), blk, 0, stream>>>(x,  w_d0, b_d0, S0,   3, 512, 512,   64, 256, 256, 1,   3, 1, 0);
  conv3_kernel<1, 4, 8, false><<<dim3( 256, 2, 2), blk, 0, stream>>>(S0, w_d1, b_d1, S1,  64, 256, 256,  128, 128, 128, 1,  64, 2, 0);
  conv3_kernel<1, 4, 8, true ><<<dim3(  64, 8, 2), blk, 0, stream>>>(S1, w_d2, b_d2, P0, 128, 128, 128,  256,  64,  64, 1,  64, 4, 2097152);
  reduce_bias_act_kernel<<<dim3(2048), blk, 0, stream>>>(S0, P0, b_d2, 524288, 4096, 256, 2, 524288, 1);
  conv3_kernel<1, 4, 8, true ><<<dim3(  16,32, 2), blk, 0, stream>>>(S0, w_d3, b_d3, P1, 256,  64,  64,  512,  32,  32, 1,  64, 8, 1048576);
  reduce_bias_act_kernel<<<dim3(1024), blk, 0, stream>>>(S1, P1, b_d3, 262144, 1024, 512, 4, 262144, 1);
  conv3_kernel<1, 4, 8, true ><<<dim3(   4,128,2), blk, 0, stream>>>(S1, w_d4, b_d4, P0, 512,  32,  32, 1024,  16,  16, 1,  64,16, 524288);
  reduce_bias_act_kernel<<<dim3( 512), blk, 0, stream>>>(S0, P0, b_d4, 131072,  256,1024, 8, 131072, 1);
  // -------- innermost conv (no act) + BN + lrelu --------
  conv3_kernel<0, 4, 8, true ><<<dim3(   4,128,2), blk, 0, stream>>>(S0, w_in, b_in, P1, 1024, 16,  16, 1024,  16,  16, 0, 128,16, 524288);
  reduce_bias_act_kernel<<<dim3( 512), blk, 0, stream>>>(S1, P1, b_in, 131072,  256,1024, 8, 131072, 0);
  bn_lrelu_kernel<<<dim3(1024), blk, 0, stream>>>(S1, gamma, beta);
  // -------- decoder (parity-decomposed up2+conv+lrelu) --------
  up_conv_kernel<1, 4, 8, false, true ><<<dim3(  16,32, 2), blk, 0, stream>>>(S1, w_u0, b_u0, P0, 1024, 16,  16,  512,  32,  32, 256, 8, 1048576, nullptr, nullptr);
  reduce_bias_act_kernel<<<dim3(1024), blk, 0, stream>>>(S0, P0, b_u0, 262144, 1024, 512, 4, 262144, 1);
  up_conv_kernel<1, 4, 8, false, true ><<<dim3(  64, 8, 2), blk, 0, stream>>>(S0, w_u1, b_u1, P1,  512, 32,  32,  256,  64,  64, 256, 4, 2097152, nullptr, nullptr);
  reduce_bias_act_kernel<<<dim3(2048), blk, 0, stream>>>(S1, P1, b_u1, 524288, 4096, 256, 2, 524288, 1);
  up_conv_kernel<1, 4, 8, false, false><<<dim3( 256, 2, 2), blk, 0, stream>>>(S1, w_u2, b_u2, S0,  256, 64,  64,  128, 128, 128, 256, 2, 0, nullptr, nullptr);
  up_conv_kernel<2, 4, 8, false, false><<<dim3( 256, 1, 2), blk, 0, stream>>>(S0, w_u3, b_u3, S1,  128, 128, 128,   64, 256, 256, 128, 1, 0, nullptr, nullptr);
  // -------- u4 + fused 1x1 epilogue -> d_out --------
  up_conv_kernel<2, 4, 8, true,  false><<<dim3(1024, 1, 2), blk, 0, stream>>>(S1, w_u4, b_u4, outp, 64, 256, 256,   64, 512, 512,  64, 1, 0, w_ep, b_ep);
}

// Round 4
// 2249.183 us; speedup vs baseline: 2.3569x; 1.4039x over previous
//
#include <hip/hip_runtime.h>
#include <math.h>

#define LRELU_SLOPE 0.01f
#define BN_EPS 1e-5f

__device__ __forceinline__ float lrelu_f(float v) { return v >= 0.f ? v : LRELU_SLOPE * v; }

// ---------------------------------------------------------------------------
// Encoder / plain conv kernel (MODE 0 = plain, MODE 1 = conv+lrelu+down2).
// Block 256, output tile 8x8 px x 64 co. K-split: blockIdx.y = seg*cogY+cog;
// each segment covers segCi input channels; PARTIAL writes raw acc to
// out + seg*seg_stride (reduce kernel applies bias+act).
// acc = 16 floats/thread -> ~60 VGPR, (256,4) is safe (no spill).
// ---------------------------------------------------------------------------
template <int MODE, int KCO, int CC, bool PARTIAL>
__global__ __launch_bounds__(256, 4) void conv3_kernel(
    const float* __restrict__ in, const float* __restrict__ wgt,
    const float* __restrict__ bias, float* __restrict__ out,
    int Cin, int Hin, int Win, int Cout, int Ho, int Wo, int apply_act,
    int segCi, int cogY, size_t seg_stride)
{
  constexpr int NCO = 16 * KCO;
  constexpr int LOG = (KCO == 4) ? 6 : 5;
  constexpr int IH  = (MODE == 1) ? 17 : 10;
  constexpr int IP  = (MODE == 1) ? 20 : 12;
  __shared__ __align__(16) float s_in[CC * IH * IP];
  __shared__ __align__(16) float s_w[CC * 9 * NCO];

  const int tid  = threadIdx.x;
  const int tx   = tid & 15;
  const int ty   = tid >> 4;
  const int trow = ty >> 1;
  const int xl0  = (ty & 1) * 4;

  const int tilesX = Wo >> 3;
  const int x0   = (blockIdx.x % tilesX) * 8;
  const int y0   = (blockIdx.x / tilesX) * 8;
  const int cog0 = (blockIdx.y % cogY) * NCO;
  const int seg  = blockIdx.y / cogY;
  const int ci_begin = seg * segCi;
  const int n    = blockIdx.z;
  if (PARTIAL) out += (size_t)seg * seg_stride;

  const size_t HWin = (size_t)Hin * Win;
  const float* inN = in + (size_t)n * Cin * HWin;

  float acc[KCO][4];
#pragma unroll
  for (int a = 0; a < KCO; a++)
#pragma unroll
    for (int b = 0; b < 4; b++) acc[a][b] = 0.f;

  for (int ci0 = 0; ci0 < segCi; ci0 += CC) {
    const int chunk = (segCi - ci0 < CC) ? (segCi - ci0) : CC;
    __syncthreads();
    // ---- stage input tile ----
    const int tot = chunk * (IH * IH);
    for (int idx = tid; idx < tot; idx += 256) {
      const int ci  = idx / (IH * IH);
      const int rem = idx - ci * (IH * IH);
      const int r   = rem / IH;
      const int c   = rem - r * IH;
      float v = 0.f;
      const int gci = ci_begin + ci0 + ci;
      if (MODE == 1) {
        const int gy = 2 * y0 - 1 + r;
        const int gx = 2 * x0 - 1 + c;
        if (gy >= 0 && gy < Hin && gx >= 0 && gx < Win)
          v = inN[(size_t)gci * HWin + (size_t)gy * Win + gx];
        const int dst = (c & 1) ? (10 + (c >> 1)) : (c >> 1);  // de-interleave
        s_in[(ci * IH + r) * IP + dst] = v;
      } else {
        const int gy = y0 - 1 + r;
        const int gx = x0 - 1 + c;
        if (gy >= 0 && gy < Hin && gx >= 0 && gx < Win)
          v = inN[(size_t)gci * HWin + (size_t)gy * Win + gx];
        s_in[(ci * IH + r) * IP + c] = v;
      }
    }
    // ---- stage weights transposed: s_w[e*NCO + co] ----
    const int e9 = chunk * 9;
    const int wtot = e9 * NCO;
    for (int idx = tid; idx < wtot; idx += 256) {
      const int co = idx & (NCO - 1);
      const int e  = idx >> LOG;
      s_w[e * NCO + co] = wgt[(size_t)(cog0 + co) * Cin * 9 + (size_t)(ci_begin + ci0) * 9 + e];
    }
    __syncthreads();

    auto body = [&](int ci) {
#pragma unroll
      for (int ky = 0; ky < 3; ky++) {
        if (MODE == 1) {
          const int base = (ci * IH + 2 * trow + ky) * IP;
          const float4 e4 = *(const float4*)&s_in[base + xl0];
          const float  e5 = s_in[base + xl0 + 4];
          const float2 oa = *(const float2*)&s_in[base + 10 + xl0];
          const float2 ob = *(const float2*)&s_in[base + 12 + xl0];
          const float ev[5] = {e4.x, e4.y, e4.z, e4.w, e5};
          const float ov[4] = {oa.x, oa.y, ob.x, ob.y};
#pragma unroll
          for (int kx = 0; kx < 3; kx++) {
            const int e = ci * 9 + ky * 3 + kx;
            float wv[KCO];
            if constexpr (KCO == 4) {
              const float4 w4 = *(const float4*)&s_w[e * 64 + (tx << 2)];
              wv[0] = w4.x; wv[1] = w4.y; wv[2] = w4.z; wv[3] = w4.w;
            } else {
              const float2 w2 = *(const float2*)&s_w[e * 32 + (tx << 1)];
              wv[0] = w2.x; wv[1] = w2.y;
            }
#pragma unroll
            for (int j = 0; j < 4; j++) {
              const float xv = (kx == 0) ? ev[j] : ((kx == 1) ? ov[j] : ev[j + 1]);
#pragma unroll
              for (int k = 0; k < KCO; k++) acc[k][j] += wv[k] * xv;
            }
          }
        } else {
          const int base = (ci * IH + trow + ky) * IP + xl0;
          const float4 a4 = *(const float4*)&s_in[base];
          const float2 a2 = *(const float2*)&s_in[base + 4];
          const float iv[6] = {a4.x, a4.y, a4.z, a4.w, a2.x, a2.y};
#pragma unroll
          for (int kx = 0; kx < 3; kx++) {
            const int e = ci * 9 + ky * 3 + kx;
            float wv[KCO];
            if constexpr (KCO == 4) {
              const float4 w4 = *(const float4*)&s_w[e * 64 + (tx << 2)];
              wv[0] = w4.x; wv[1] = w4.y; wv[2] = w4.z; wv[3] = w4.w;
            } else {
              const float2 w2 = *(const float2*)&s_w[e * 32 + (tx << 1)];
              wv[0] = w2.x; wv[1] = w2.y;
            }
#pragma unroll
            for (int j = 0; j < 4; j++) {
              const float xv = iv[j + kx];
#pragma unroll
              for (int k = 0; k < KCO; k++) acc[k][j] += wv[k] * xv;
            }
          }
        }
      }
    };
    if (chunk == CC) {
#pragma unroll
      for (int ci = 0; ci < CC; ci++) body(ci);
    } else {
      for (int ci = 0; ci < chunk; ci++) body(ci);  // only d0 (Cin=3)
    }
  }

#pragma unroll
  for (int k = 0; k < KCO; k++) {
    const int co = cog0 + tx * KCO + k;
    float* op = out + ((size_t)((size_t)n * Cout + co) * Ho + (y0 + trow)) * Wo + x0 + xl0;
    float4 v;
    if constexpr (PARTIAL) {
      v.x = acc[k][0]; v.y = acc[k][1]; v.z = acc[k][2]; v.w = acc[k][3];
    } else {
      const float b = bias[co];
      v.x = acc[k][0] + b; v.y = acc[k][1] + b; v.z = acc[k][2] + b; v.w = acc[k][3] + b;
      if (apply_act) { v.x = lrelu_f(v.x); v.y = lrelu_f(v.y); v.z = lrelu_f(v.z); v.w = lrelu_f(v.w); }
    }
    *reinterpret_cast<float4*>(op) = v;
  }
}

// ---------------------------------------------------------------------------
// Decoder kernel: zero-insert up2 + conv3x3 (+lrelu), parity-decomposed.
// NQ=2 needs 64 acc floats/thread -> launch_bounds (256,2) so the allocator
// has ~110 VGPRs WITHOUT spilling to scratch. (R3 post-mortem: (256,4) capped
// VGPR at 64 and spilled acc -> 4.7 GB of scratch HBM traffic per dispatch.)
// EPI: epilogue 1x1 (64->3) via shfl-reduce + LDS transpose + coalesced
// float4 stores (replaces scattered 4B stores).
// ---------------------------------------------------------------------------
template <int NQ, int KCO, int CC, bool EPI, bool PARTIAL>
__global__ __launch_bounds__(256, 2) void up_conv_kernel(
    const float* __restrict__ in, const float* __restrict__ wgt,
    const float* __restrict__ bias, float* __restrict__ out,
    int Cin, int Hin, int Win, int Cout, int Ho, int Wo,
    int segCi, int cogY, size_t seg_stride,
    const float* __restrict__ w_ep, const float* __restrict__ b_ep)
{
  constexpr int NCO = 16 * KCO;
  constexpr int LOG = (KCO == 4) ? 6 : 5;
  constexpr int TQ = 2 * NQ;
  constexpr int T  = 4 * TQ;
  constexpr int IR = 4 * NQ + 1;
  constexpr int PR = IR + 1;
  __shared__ __align__(16) float s_in[CC * IR * PR];
  __shared__ __align__(16) float s_w[CC * 9 * NCO];
  __shared__ float s_epi[EPI ? 3 * 16 * 17 : 1];

  const int tid = threadIdx.x;
  const int tx  = tid & 15;
  const int ty  = tid >> 4;
  const int Qy  = ty >> 2;
  const int Qx  = ty & 3;

  const int tilesX = Wo / T;
  const int x0   = (blockIdx.x % tilesX) * T;
  const int y0   = (blockIdx.x / tilesX) * T;
  const int cog0 = (blockIdx.y % cogY) * NCO;
  const int seg  = blockIdx.y / cogY;
  const int ci_begin = seg * segCi;
  const int n    = blockIdx.z;
  if (PARTIAL) out += (size_t)seg * seg_stride;
  const int r0 = y0 >> 1;
  const int c0 = x0 >> 1;

  const size_t HWin = (size_t)Hin * Win;
  const float* inN = in + (size_t)n * Cin * HWin;

  float acc[KCO][TQ][TQ];
#pragma unroll
  for (int k = 0; k < KCO; k++)
#pragma unroll
    for (int i = 0; i < TQ; i++)
#pragma unroll
      for (int j = 0; j < TQ; j++) acc[k][i][j] = 0.f;

  for (int ci0 = 0; ci0 < segCi; ci0 += CC) {
    __syncthreads();
    // ---- stage raw (non-zero-inserted) input tile, zero-pad hi edge ----
    const int tot = CC * (IR * IR);
    for (int idx = tid; idx < tot; idx += 256) {
      const int ci  = idx / (IR * IR);
      const int rem = idx - ci * (IR * IR);
      const int r   = rem / IR;
      const int c   = rem - r * IR;
      const int gy = r0 + r, gx = c0 + c;
      float v = 0.f;
      if (gy < Hin && gx < Win)
        v = inN[(size_t)(ci_begin + ci0 + ci) * HWin + (size_t)gy * Win + gx];
      s_in[(ci * IR + r) * PR + c] = v;
    }
    // ---- stage weights transposed ----
    const int wtot = CC * 9 * NCO;
    for (int idx = tid; idx < wtot; idx += 256) {
      const int co = idx & (NCO - 1);
      const int e  = idx >> LOG;
      s_w[e * NCO + co] = wgt[(size_t)(cog0 + co) * Cin * 9 + (size_t)(ci_begin + ci0) * 9 + e];
    }
    __syncthreads();

#pragma unroll
    for (int ci = 0; ci < CC; ci++) {
      float iv[NQ + 1][NQ + 1];
#pragma unroll
      for (int dr = 0; dr <= NQ; dr++)
#pragma unroll
        for (int dc = 0; dc <= NQ; dc++)
          iv[dr][dc] = s_in[(ci * IR + NQ * Qy + dr) * PR + NQ * Qx + dc];
#pragma unroll
      for (int t = 0; t < 9; t++) {
        const int ky = t / 3, kx = t % 3;
        float wv[KCO];
        if constexpr (KCO == 4) {
          const float4 w4 = *(const float4*)&s_w[(ci * 9 + t) * 64 + (tx << 2)];
          wv[0] = w4.x; wv[1] = w4.y; wv[2] = w4.z; wv[3] = w4.w;
        } else {
          const float2 w2 = *(const float2*)&s_w[(ci * 9 + t) * 32 + (tx << 1)];
          wv[0] = w2.x; wv[1] = w2.y;
        }
        const int pr  = (ky == 1) ? 0 : 1;
        const int drr = (ky == 2) ? 1 : 0;
        const int pc  = (kx == 1) ? 0 : 1;
        const int dcc = (kx == 2) ? 1 : 0;
#pragma unroll
        for (int a = 0; a < NQ; a++)
#pragma unroll
          for (int b = 0; b < NQ; b++) {
            const float xv = iv[a + drr][b + dcc];
#pragma unroll
            for (int k = 0; k < KCO; k++)
              acc[k][2 * a + pr][2 * b + pc] += wv[k] * xv;
          }
      }
    }
  }

  if (!EPI) {
#pragma unroll
    for (int k = 0; k < KCO; k++) {
      const int co = cog0 + tx * KCO + k;
      const float bv = PARTIAL ? 0.f : bias[co];
#pragma unroll
      for (int i = 0; i < TQ; i++) {
        const int y = y0 + TQ * Qy + i;
        float* op = out + ((size_t)((size_t)n * Cout + co) * Ho + y) * Wo + x0 + TQ * Qx;
        if constexpr (NQ == 2) {
          float4 v;
          if constexpr (PARTIAL) {
            v.x = acc[k][i][0]; v.y = acc[k][i][1]; v.z = acc[k][i][2]; v.w = acc[k][i][3];
          } else {
            v.x = lrelu_f(acc[k][i][0] + bv); v.y = lrelu_f(acc[k][i][1] + bv);
            v.z = lrelu_f(acc[k][i][2] + bv); v.w = lrelu_f(acc[k][i][3] + bv);
          }
          *reinterpret_cast<float4*>(op) = v;
        } else {
          float2 v;
          if constexpr (PARTIAL) {
            v.x = acc[k][i][0]; v.y = acc[k][i][1];
          } else {
            v.x = lrelu_f(acc[k][i][0] + bv); v.y = lrelu_f(acc[k][i][1] + bv);
          }
          *reinterpret_cast<float2*>(op) = v;
        }
      }
    }
  } else {
    // ---- fused 1x1 (64->3) epilogue: shfl-reduce over the 16 co-lanes,
    //      park in LDS, then coalesced float4 stores. Params loaded late
    //      (keeps them out of the main loop's live range). ----
    float wep[3][KCO];
#pragma unroll
    for (int o = 0; o < 3; o++)
#pragma unroll
      for (int k = 0; k < KCO; k++) wep[o][k] = w_ep[o * 64 + tx * KCO + k];
    const float bv[KCO] = {bias[tx * KCO + 0], bias[tx * KCO + 1],
                           bias[tx * KCO + 2], bias[tx * KCO + 3]};
    __syncthreads();  // done with s_in/s_w reads before any s_epi aliasing issues
#pragma unroll
    for (int i = 0; i < TQ; i++)
#pragma unroll
      for (int j = 0; j < TQ; j++) {
        float h[KCO];
#pragma unroll
        for (int k = 0; k < KCO; k++) h[k] = lrelu_f(acc[k][i][j] + bv[k]);
        float s0 = 0.f, s1 = 0.f, s2 = 0.f;
#pragma unroll
        for (int k = 0; k < KCO; k++) {
          s0 += wep[0][k] * h[k]; s1 += wep[1][k] * h[k]; s2 += wep[2][k] * h[k];
        }
#pragma unroll
        for (int m = 1; m < 16; m <<= 1) {
          s0 += __shfl_xor(s0, m); s1 += __shfl_xor(s1, m); s2 += __shfl_xor(s2, m);
        }
        if (tx < 3) {
          const float sv = (tx == 0) ? s0 : ((tx == 1) ? s1 : s2);
          s_epi[tx * 272 + (TQ * Qy + i) * 17 + TQ * Qx + j] = sv;
        }
      }
    __syncthreads();
    if (tid < 192) {
      const int o   = tid >> 6;         // wave-uniform (3 waves active)
      const int rem = tid & 63;
      const int row = rem >> 2;
      const int xq  = (rem & 3) << 2;
      const float be = b_ep[o];
      float4 v;
      v.x = s_epi[o * 272 + row * 17 + xq + 0] + be;
      v.y = s_epi[o * 272 + row * 17 + xq + 1] + be;
      v.z = s_epi[o * 272 + row * 17 + xq + 2] + be;
      v.w = s_epi[o * 272 + row * 17 + xq + 3] + be;
      float* op = out + ((size_t)((size_t)n * 3 + o) * Ho + (y0 + row)) * Wo + x0 + xq;
      *reinterpret_cast<float4*>(op) = v;
    }
  }
}

// ---------------------------------------------------------------------------
// Sum K-split partials + bias (+lrelu), vectorized float4.
// ---------------------------------------------------------------------------
__global__ __launch_bounds__(256) void reduce_bias_act_kernel(
    float* __restrict__ dst, const float* __restrict__ part,
    const float* __restrict__ bias, int total4, int HW, int Cout,
    int S, int seg_stride4, int act)
{
  const int i = blockIdx.x * 256 + threadIdx.x;
  if (i >= total4) return;
  const float4* p = (const float4*)part;
  float4 s = p[i];
  for (int k = 1; k < S; k++) {
    const float4 v = p[i + (size_t)k * seg_stride4];
    s.x += v.x; s.y += v.y; s.z += v.z; s.w += v.w;
  }
  const int co = ((i << 2) / HW) % Cout;
  const float b = bias[co];
  s.x += b; s.y += b; s.z += b; s.w += b;
  if (act) { s.x = lrelu_f(s.x); s.y = lrelu_f(s.y); s.z = lrelu_f(s.z); s.w = lrelu_f(s.w); }
  ((float4*)dst)[i] = s;
}

// BatchNorm (batch stats over N,H,W) + LeakyReLU, in place. 1 block/channel.
__global__ __launch_bounds__(256) void bn_lrelu_kernel(
    float* __restrict__ h, const float* __restrict__ gamma, const float* __restrict__ beta)
{
  const int c = blockIdx.x;
  const int t = threadIdx.x;
  const size_t i0 = (size_t)c * 256 + t;
  const size_t i1 = (size_t)(1024 + c) * 256 + t;
  const float v0 = h[i0], v1 = h[i1];
  float s = v0 + v1;
  float q = v0 * v0 + v1 * v1;
  for (int o = 32; o > 0; o >>= 1) { s += __shfl_down(s, o); q += __shfl_down(q, o); }
  __shared__ float sh[8];
  __shared__ float param[2];
  const int wid = t >> 6, lane = t & 63;
  if (lane == 0) { sh[wid] = s; sh[4 + wid] = q; }
  __syncthreads();
  if (t == 0) {
    const float S = sh[0] + sh[1] + sh[2] + sh[3];
    const float Q = sh[4] + sh[5] + sh[6] + sh[7];
    const float mean = S * (1.f / 512.f);
    const float var = Q * (1.f / 512.f) - mean * mean;
    const float scale = gamma[c] / sqrtf(var + BN_EPS);
    param[0] = scale;
    param[1] = beta[c] - mean * scale;
  }
  __syncthreads();
  const float sc = param[0], sf = param[1];
  h[i0] = lrelu_f(v0 * sc + sf);
  h[i1] = lrelu_f(v1 * sc + sf);
}

extern "C" void kernel_launch(void* const* d_in, const int* in_sizes, int n_in,
                              void* d_out, int out_size, void* d_ws, size_t ws_size,
                              hipStream_t stream)
{
  (void)in_sizes; (void)n_in; (void)out_size; (void)ws_size;
  const float* x     = (const float*)d_in[0];
  const float* w_d0  = (const float*)d_in[1];
  const float* b_d0  = (const float*)d_in[2];
  const float* w_d1  = (const float*)d_in[3];
  const float* b_d1  = (const float*)d_in[4];
  const float* w_d2  = (const float*)d_in[5];
  const float* b_d2  = (const float*)d_in[6];
  const float* w_d3  = (const float*)d_in[7];
  const float* b_d3  = (const float*)d_in[8];
  const float* w_d4  = (const float*)d_in[9];
  const float* b_d4  = (const float*)d_in[10];
  const float* w_in  = (const float*)d_in[11];
  const float* b_in  = (const float*)d_in[12];
  const float* gamma = (const float*)d_in[13];
  const float* beta  = (const float*)d_in[14];
  const float* w_u0  = (const float*)d_in[15];
  const float* b_u0  = (const float*)d_in[16];
  const float* w_u1  = (const float*)d_in[17];
  const float* b_u1  = (const float*)d_in[18];
  const float* w_u2  = (const float*)d_in[19];
  const float* b_u2  = (const float*)d_in[20];
  const float* w_u3  = (const float*)d_in[21];
  const float* b_u3  = (const float*)d_in[22];
  const float* w_u4  = (const float*)d_in[23];
  const float* b_u4  = (const float*)d_in[24];
  const float* w_ep  = (const float*)d_in[25];
  const float* b_ep  = (const float*)d_in[26];

  // ws layout: two 32 MiB ping-pong slots; K-split partials (<=16.8 MB) live
  // in the DESTINATION slot at +12 MiB (dst region itself is <=8.4 MB).
  float* S0 = (float*)d_ws;
  float* S1 = (float*)((char*)d_ws + (size_t)33554432);
  float* P0 = S0 + 3145728;   // S0 + 12 MiB
  float* P1 = S1 + 3145728;   // S1 + 12 MiB
  float* outp = (float*)d_out;

  const dim3 blk(256);
  // -------- encoder (conv+lrelu+down2 fused) --------
  conv3_kernel<1, 4, 4, false><<<dim3(1024, 1, 2), blk, 0, stream>>>(x,  w_d0, b_d0, S0,   3, 512, 512,   64, 256, 256, 1,   3, 1, 0);
  conv3_kernel<1, 4, 8, false><<<dim3( 256, 2, 2), blk, 0, stream>>>(S0, w_d1, b_d1, S1,  64, 256, 256,  128, 128, 128, 1,  64, 2, 0);
  conv3_kernel<1, 4, 8, true ><<<dim3(  64, 8, 2), blk, 0, stream>>>(S1, w_d2, b_d2, P0, 128, 128, 128,  256,  64,  64, 1,  64, 4, 2097152);
  reduce_bias_act_kernel<<<dim3(2048), blk, 0, stream>>>(S0, P0, b_d2, 524288, 4096, 256, 2, 524288, 1);
  conv3_kernel<1, 4, 8, true ><<<dim3(  16,32, 2), blk, 0, stream>>>(S0, w_d3, b_d3, P1, 256,  64,  64,  512,  32,  32, 1,  64, 8, 1048576);
  reduce_bias_act_kernel<<<dim3(1024), blk, 0, stream>>>(S1, P1, b_d3, 262144, 1024, 512, 4, 262144, 1);
  conv3_kernel<1, 4, 8, true ><<<dim3(   4,128,2), blk, 0, stream>>>(S1, w_d4, b_d4, P0, 512,  32,  32, 1024,  16,  16, 1,  64,16, 524288);
  reduce_bias_act_kernel<<<dim3( 512), blk, 0, stream>>>(S0, P0, b_d4, 131072,  256,1024, 8, 131072, 1);
  // -------- innermost conv (no act) + BN + lrelu --------
  conv3_kernel<0, 4, 8, true ><<<dim3(   4,128,2), blk, 0, stream>>>(S0, w_in, b_in, P1, 1024, 16,  16, 1024,  16,  16, 0, 128,16, 524288);
  reduce_bias_act_kernel<<<dim3( 512), blk, 0, stream>>>(S1, P1, b_in, 131072,  256,1024, 8, 131072, 0);
  bn_lrelu_kernel<<<dim3(1024), blk, 0, stream>>>(S1, gamma, beta);
  // -------- decoder (parity-decomposed up2+conv+lrelu) --------
  up_conv_kernel<1, 4, 8, false, true ><<<dim3(  16,32, 2), blk, 0, stream>>>(S1, w_u0, b_u0, P0, 1024, 16,  16,  512,  32,  32, 256, 8, 1048576, nullptr, nullptr);
  reduce_bias_act_kernel<<<dim3(1024), blk, 0, stream>>>(S0, P0, b_u0, 262144, 1024, 512, 4, 262144, 1);
  up_conv_kernel<1, 4, 8, false, true ><<<dim3(  64, 8, 2), blk, 0, stream>>>(S0, w_u1, b_u1, P1,  512, 32,  32,  256,  64,  64, 256, 4, 2097152, nullptr, nullptr);
  reduce_bias_act_kernel<<<dim3(2048), blk, 0, stream>>>(S1, P1, b_u1, 524288, 4096, 256, 2, 524288, 1);
  up_conv_kernel<1, 4, 8, false, false><<<dim3( 256, 2, 2), blk, 0, stream>>>(S1, w_u2, b_u2, S0,  256, 64,  64,  128, 128, 128, 256, 2, 0, nullptr, nullptr);
  up_conv_kernel<2, 4, 8, false, false><<<dim3( 256, 1, 2), blk, 0, stream>>>(S0, w_u3, b_u3, S1,  128, 128, 128,   64, 256, 256, 128, 1, 0, nullptr, nullptr);
  // -------- u4 + fused 1x1 epilogue -> d_out --------
  up_conv_kernel<2, 4, 8, true,  false><<<dim3(1024, 1, 2), blk, 0, stream>>>(S1, w_u4, b_u4, outp, 64, 256, 256,   64, 512, 512,  64, 1, 0, w_ep, b_ep);
}

// Round 5
// 1741.489 us; speedup vs baseline: 3.0441x; 1.2915x over previous
//
#include <hip/hip_runtime.h>
#include <math.h>

#define LRELU_SLOPE 0.01f
#define BN_EPS 1e-5f

__device__ __forceinline__ float lrelu_f(float v) { return v >= 0.f ? v : LRELU_SLOPE * v; }

// ---------------------------------------------------------------------------
// Encoder / plain conv kernel, 8-wide: thread = 4 co x 8 px (one row).
// Block 256 = tile 16w x 8h x 64 co. MODE 0 plain, MODE 1 conv+lrelu+down2.
// MODE1 input staged de-interleaved: even cols [0..16], odd cols [20..35],
// pitch 36 (mult of 4 -> aligned b128 reads). K-split via segCi/cogY/stride.
// acc 32 + ev/ov 17 + misc ~ 90 VGPR -> (256,2), no spill.
// ---------------------------------------------------------------------------
template <int MODE, int CC, bool PARTIAL>
__global__ __launch_bounds__(256, 2) void conv3_kernel(
    const float* __restrict__ in, const float* __restrict__ wgt,
    const float* __restrict__ bias, float* __restrict__ out,
    int Cin, int Hin, int Win, int Cout, int Ho, int Wo, int apply_act,
    int segCi, int cogY, size_t seg_stride)
{
  constexpr int IH = (MODE == 1) ? 17 : 10;
  constexpr int IW = (MODE == 1) ? 33 : 18;
  constexpr int IP = (MODE == 1) ? 36 : 20;
  __shared__ __align__(16) float s_in[CC * IH * IP];
  __shared__ __align__(16) float s_w[CC * 9 * 64];

  const int tid = threadIdx.x;
  const int tx  = tid & 15;          // co group (4 co)
  const int ty  = tid >> 4;
  const int row = ty >> 1;           // 0..7
  const int xh  = (ty & 1) * 8;      // 0 or 8

  const int tilesX = Wo >> 4;
  const int x0   = (blockIdx.x % tilesX) * 16;
  const int y0   = (blockIdx.x / tilesX) * 8;
  const int cog0 = (blockIdx.y % cogY) * 64;
  const int seg  = blockIdx.y / cogY;
  const int ci_begin = seg * segCi;
  const int n    = blockIdx.z;
  if (PARTIAL) out += (size_t)seg * seg_stride;

  const size_t HWin = (size_t)Hin * Win;
  const float* inN = in + (size_t)n * Cin * HWin;

  float acc[4][8];
#pragma unroll
  for (int a = 0; a < 4; a++)
#pragma unroll
    for (int b = 0; b < 8; b++) acc[a][b] = 0.f;

  for (int ci0 = 0; ci0 < segCi; ci0 += CC) {
    const int chunk = (segCi - ci0 < CC) ? (segCi - ci0) : CC;
    __syncthreads();
    // ---- stage input tile ----
    const int tot = chunk * (IH * IW);
    for (int idx = tid; idx < tot; idx += 256) {
      const int ci  = idx / (IH * IW);
      const int rem = idx - ci * (IH * IW);
      const int r   = rem / IW;
      const int c   = rem - r * IW;
      float v = 0.f;
      const int gci = ci_begin + ci0 + ci;
      if (MODE == 1) {
        const int gy = 2 * y0 - 1 + r;
        const int gx = 2 * x0 - 1 + c;
        if (gy >= 0 && gy < Hin && gx >= 0 && gx < Win)
          v = inN[(size_t)gci * HWin + (size_t)gy * Win + gx];
        const int dst = (c & 1) ? (20 + (c >> 1)) : (c >> 1);  // de-interleave
        s_in[(ci * IH + r) * IP + dst] = v;
      } else {
        const int gy = y0 - 1 + r;
        const int gx = x0 - 1 + c;
        if (gy >= 0 && gy < Hin && gx >= 0 && gx < Win)
          v = inN[(size_t)gci * HWin + (size_t)gy * Win + gx];
        s_in[(ci * IH + r) * IP + c] = v;
      }
    }
    // ---- stage weights transposed: s_w[e*64 + co] ----
    const int e9 = chunk * 9;
    const int wtot = e9 * 64;
    for (int idx = tid; idx < wtot; idx += 256) {
      const int co = idx & 63;
      const int e  = idx >> 6;
      s_w[e * 64 + co] = wgt[(size_t)(cog0 + co) * Cin * 9 + (size_t)(ci_begin + ci0) * 9 + e];
    }
    __syncthreads();

    auto body = [&](int ci) {
#pragma unroll
      for (int ky = 0; ky < 3; ky++) {
        if (MODE == 1) {
          const int base = (ci * IH + 2 * row + ky) * IP;
          const float4 ea = *(const float4*)&s_in[base + xh];
          const float4 eb = *(const float4*)&s_in[base + xh + 4];
          const float  e8 = s_in[base + xh + 8];
          const float4 oa = *(const float4*)&s_in[base + 20 + xh];
          const float4 ob = *(const float4*)&s_in[base + 24 + xh];
          const float ev[9] = {ea.x, ea.y, ea.z, ea.w, eb.x, eb.y, eb.z, eb.w, e8};
          const float ov[8] = {oa.x, oa.y, oa.z, oa.w, ob.x, ob.y, ob.z, ob.w};
#pragma unroll
          for (int kx = 0; kx < 3; kx++) {
            const int e = ci * 9 + ky * 3 + kx;
            const float4 w4 = *(const float4*)&s_w[e * 64 + (tx << 2)];
            const float wv[4] = {w4.x, w4.y, w4.z, w4.w};
#pragma unroll
            for (int j = 0; j < 8; j++) {
              const float xv = (kx == 0) ? ev[j] : ((kx == 1) ? ov[j] : ev[j + 1]);
#pragma unroll
              for (int k = 0; k < 4; k++) acc[k][j] += wv[k] * xv;
            }
          }
        } else {
          const int base = (ci * IH + row + ky) * IP + xh;
          const float4 a4 = *(const float4*)&s_in[base];
          const float4 b4 = *(const float4*)&s_in[base + 4];
          const float2 c2 = *(const float2*)&s_in[base + 8];
          const float iv[10] = {a4.x, a4.y, a4.z, a4.w, b4.x, b4.y, b4.z, b4.w, c2.x, c2.y};
#pragma unroll
          for (int kx = 0; kx < 3; kx++) {
            const int e = ci * 9 + ky * 3 + kx;
            const float4 w4 = *(const float4*)&s_w[e * 64 + (tx << 2)];
            const float wv[4] = {w4.x, w4.y, w4.z, w4.w};
#pragma unroll
            for (int j = 0; j < 8; j++) {
              const float xv = iv[j + kx];
#pragma unroll
              for (int k = 0; k < 4; k++) acc[k][j] += wv[k] * xv;
            }
          }
        }
      }
    };
    if (chunk == CC) {
#pragma unroll
      for (int ci = 0; ci < CC; ci++) body(ci);
    } else {
      for (int ci = 0; ci < chunk; ci++) body(ci);  // d0 (Cin=3)
    }
  }

#pragma unroll
  for (int k = 0; k < 4; k++) {
    const int co = cog0 + tx * 4 + k;
    float* op = out + ((size_t)((size_t)n * Cout + co) * Ho + (y0 + row)) * Wo + x0 + xh;
    float4 v0, v1;
    if constexpr (PARTIAL) {
      v0.x = acc[k][0]; v0.y = acc[k][1]; v0.z = acc[k][2]; v0.w = acc[k][3];
      v1.x = acc[k][4]; v1.y = acc[k][5]; v1.z = acc[k][6]; v1.w = acc[k][7];
    } else {
      const float b = bias[co];
      v0.x = acc[k][0] + b; v0.y = acc[k][1] + b; v0.z = acc[k][2] + b; v0.w = acc[k][3] + b;
      v1.x = acc[k][4] + b; v1.y = acc[k][5] + b; v1.z = acc[k][6] + b; v1.w = acc[k][7] + b;
      if (apply_act) {
        v0.x = lrelu_f(v0.x); v0.y = lrelu_f(v0.y); v0.z = lrelu_f(v0.z); v0.w = lrelu_f(v0.w);
        v1.x = lrelu_f(v1.x); v1.y = lrelu_f(v1.y); v1.z = lrelu_f(v1.z); v1.w = lrelu_f(v1.w);
      }
    }
    *reinterpret_cast<float4*>(op) = v0;
    *reinterpret_cast<float4*>(op + 4) = v1;
  }
}

// ---------------------------------------------------------------------------
// Decoder kernel: zero-insert up2 + conv3x3 (+lrelu), parity-decomposed.
// (256,2): NQ=2 needs ~110 VGPR live (acc 64) -- do not tighten (R3 lesson).
// ---------------------------------------------------------------------------
template <int NQ, int KCO, int CC, bool EPI, bool PARTIAL>
__global__ __launch_bounds__(256, 2) void up_conv_kernel(
    const float* __restrict__ in, const float* __restrict__ wgt,
    const float* __restrict__ bias, float* __restrict__ out,
    int Cin, int Hin, int Win, int Cout, int Ho, int Wo,
    int segCi, int cogY, size_t seg_stride,
    const float* __restrict__ w_ep, const float* __restrict__ b_ep)
{
  constexpr int NCO = 16 * KCO;
  constexpr int LOG = (KCO == 4) ? 6 : 5;
  constexpr int TQ = 2 * NQ;
  constexpr int T  = 4 * TQ;
  constexpr int IR = 4 * NQ + 1;
  constexpr int PR = IR + 1;
  __shared__ __align__(16) float s_in[CC * IR * PR];
  __shared__ __align__(16) float s_w[CC * 9 * NCO];
  __shared__ float s_epi[EPI ? 3 * 16 * 17 : 1];

  const int tid = threadIdx.x;
  const int tx  = tid & 15;
  const int ty  = tid >> 4;
  const int Qy  = ty >> 2;
  const int Qx  = ty & 3;

  const int tilesX = Wo / T;
  const int x0   = (blockIdx.x % tilesX) * T;
  const int y0   = (blockIdx.x / tilesX) * T;
  const int cog0 = (blockIdx.y % cogY) * NCO;
  const int seg  = blockIdx.y / cogY;
  const int ci_begin = seg * segCi;
  const int n    = blockIdx.z;
  if (PARTIAL) out += (size_t)seg * seg_stride;
  const int r0 = y0 >> 1;
  const int c0 = x0 >> 1;

  const size_t HWin = (size_t)Hin * Win;
  const float* inN = in + (size_t)n * Cin * HWin;

  float acc[KCO][TQ][TQ];
#pragma unroll
  for (int k = 0; k < KCO; k++)
#pragma unroll
    for (int i = 0; i < TQ; i++)
#pragma unroll
      for (int j = 0; j < TQ; j++) acc[k][i][j] = 0.f;

  for (int ci0 = 0; ci0 < segCi; ci0 += CC) {
    __syncthreads();
    // ---- stage raw (non-zero-inserted) input tile, zero-pad hi edge ----
    const int tot = CC * (IR * IR);
    for (int idx = tid; idx < tot; idx += 256) {
      const int ci  = idx / (IR * IR);
      const int rem = idx - ci * (IR * IR);
      const int r   = rem / IR;
      const int c   = rem - r * IR;
      const int gy = r0 + r, gx = c0 + c;
      float v = 0.f;
      if (gy < Hin && gx < Win)
        v = inN[(size_t)(ci_begin + ci0 + ci) * HWin + (size_t)gy * Win + gx];
      s_in[(ci * IR + r) * PR + c] = v;
    }
    // ---- stage weights transposed ----
    const int wtot = CC * 9 * NCO;
    for (int idx = tid; idx < wtot; idx += 256) {
      const int co = idx & (NCO - 1);
      const int e  = idx >> LOG;
      s_w[e * NCO + co] = wgt[(size_t)(cog0 + co) * Cin * 9 + (size_t)(ci_begin + ci0) * 9 + e];
    }
    __syncthreads();

#pragma unroll
    for (int ci = 0; ci < CC; ci++) {
      float iv[NQ + 1][NQ + 1];
#pragma unroll
      for (int dr = 0; dr <= NQ; dr++)
#pragma unroll
        for (int dc = 0; dc <= NQ; dc++)
          iv[dr][dc] = s_in[(ci * IR + NQ * Qy + dr) * PR + NQ * Qx + dc];
#pragma unroll
      for (int t = 0; t < 9; t++) {
        const int ky = t / 3, kx = t % 3;
        float wv[KCO];
        if constexpr (KCO == 4) {
          const float4 w4 = *(const float4*)&s_w[(ci * 9 + t) * 64 + (tx << 2)];
          wv[0] = w4.x; wv[1] = w4.y; wv[2] = w4.z; wv[3] = w4.w;
        } else {
          const float2 w2 = *(const float2*)&s_w[(ci * 9 + t) * 32 + (tx << 1)];
          wv[0] = w2.x; wv[1] = w2.y;
        }
        const int pr  = (ky == 1) ? 0 : 1;
        const int drr = (ky == 2) ? 1 : 0;
        const int pc  = (kx == 1) ? 0 : 1;
        const int dcc = (kx == 2) ? 1 : 0;
#pragma unroll
        for (int a = 0; a < NQ; a++)
#pragma unroll
          for (int b = 0; b < NQ; b++) {
            const float xv = iv[a + drr][b + dcc];
#pragma unroll
            for (int k = 0; k < KCO; k++)
              acc[k][2 * a + pr][2 * b + pc] += wv[k] * xv;
          }
      }
    }
  }

  if (!EPI) {
#pragma unroll
    for (int k = 0; k < KCO; k++) {
      const int co = cog0 + tx * KCO + k;
      const float bv = PARTIAL ? 0.f : bias[co];
#pragma unroll
      for (int i = 0; i < TQ; i++) {
        const int y = y0 + TQ * Qy + i;
        float* op = out + ((size_t)((size_t)n * Cout + co) * Ho + y) * Wo + x0 + TQ * Qx;
        if constexpr (NQ == 2) {
          float4 v;
          if constexpr (PARTIAL) {
            v.x = acc[k][i][0]; v.y = acc[k][i][1]; v.z = acc[k][i][2]; v.w = acc[k][i][3];
          } else {
            v.x = lrelu_f(acc[k][i][0] + bv); v.y = lrelu_f(acc[k][i][1] + bv);
            v.z = lrelu_f(acc[k][i][2] + bv); v.w = lrelu_f(acc[k][i][3] + bv);
          }
          *reinterpret_cast<float4*>(op) = v;
        } else {
          float2 v;
          if constexpr (PARTIAL) {
            v.x = acc[k][i][0]; v.y = acc[k][i][1];
          } else {
            v.x = lrelu_f(acc[k][i][0] + bv); v.y = lrelu_f(acc[k][i][1] + bv);
          }
          *reinterpret_cast<float2*>(op) = v;
        }
      }
    }
  } else {
    // ---- fused 1x1 (64->3): shfl-reduce over 16 co-lanes -> LDS -> float4 ----
    float wep[3][KCO];
#pragma unroll
    for (int o = 0; o < 3; o++)
#pragma unroll
      for (int k = 0; k < KCO; k++) wep[o][k] = w_ep[o * 64 + tx * KCO + k];
    const float bv[KCO] = {bias[tx * KCO + 0], bias[tx * KCO + 1],
                           bias[tx * KCO + 2], bias[tx * KCO + 3]};
    __syncthreads();
#pragma unroll
    for (int i = 0; i < TQ; i++)
#pragma unroll
      for (int j = 0; j < TQ; j++) {
        float h[KCO];
#pragma unroll
        for (int k = 0; k < KCO; k++) h[k] = lrelu_f(acc[k][i][j] + bv[k]);
        float s0 = 0.f, s1 = 0.f, s2 = 0.f;
#pragma unroll
        for (int k = 0; k < KCO; k++) {
          s0 += wep[0][k] * h[k]; s1 += wep[1][k] * h[k]; s2 += wep[2][k] * h[k];
        }
#pragma unroll
        for (int m = 1; m < 16; m <<= 1) {
          s0 += __shfl_xor(s0, m); s1 += __shfl_xor(s1, m); s2 += __shfl_xor(s2, m);
        }
        if (tx < 3) {
          const float sv = (tx == 0) ? s0 : ((tx == 1) ? s1 : s2);
          s_epi[tx * 272 + (TQ * Qy + i) * 17 + TQ * Qx + j] = sv;
        }
      }
    __syncthreads();
    if (tid < 192) {
      const int o   = tid >> 6;
      const int rem = tid & 63;
      const int row = rem >> 2;
      const int xq  = (rem & 3) << 2;
      const float be = b_ep[o];
      float4 v;
      v.x = s_epi[o * 272 + row * 17 + xq + 0] + be;
      v.y = s_epi[o * 272 + row * 17 + xq + 1] + be;
      v.z = s_epi[o * 272 + row * 17 + xq + 2] + be;
      v.w = s_epi[o * 272 + row * 17 + xq + 3] + be;
      float* op = out + ((size_t)((size_t)n * 3 + o) * Ho + (y0 + row)) * Wo + x0 + xq;
      *reinterpret_cast<float4*>(op) = v;
    }
  }
}

// Sum K-split partials + bias (+lrelu), float4.
__global__ __launch_bounds__(256) void reduce_bias_act_kernel(
    float* __restrict__ dst, const float* __restrict__ part,
    const float* __restrict__ bias, int total4, int HW, int Cout,
    int S, int seg_stride4, int act)
{
  const int i = blockIdx.x * 256 + threadIdx.x;
  if (i >= total4) return;
  const float4* p = (const float4*)part;
  float4 s = p[i];
  for (int k = 1; k < S; k++) {
    const float4 v = p[i + (size_t)k * seg_stride4];
    s.x += v.x; s.y += v.y; s.z += v.z; s.w += v.w;
  }
  const int co = ((i << 2) / HW) % Cout;
  const float b = bias[co];
  s.x += b; s.y += b; s.z += b; s.w += b;
  if (act) { s.x = lrelu_f(s.x); s.y = lrelu_f(s.y); s.z = lrelu_f(s.z); s.w = lrelu_f(s.w); }
  ((float4*)dst)[i] = s;
}

// BatchNorm (batch stats) + LeakyReLU, in place. 1 block/channel.
__global__ __launch_bounds__(256) void bn_lrelu_kernel(
    float* __restrict__ h, const float* __restrict__ gamma, const float* __restrict__ beta)
{
  const int c = blockIdx.x;
  const int t = threadIdx.x;
  const size_t i0 = (size_t)c * 256 + t;
  const size_t i1 = (size_t)(1024 + c) * 256 + t;
  const float v0 = h[i0], v1 = h[i1];
  float s = v0 + v1;
  float q = v0 * v0 + v1 * v1;
  for (int o = 32; o > 0; o >>= 1) { s += __shfl_down(s, o); q += __shfl_down(q, o); }
  __shared__ float sh[8];
  __shared__ float param[2];
  const int wid = t >> 6, lane = t & 63;
  if (lane == 0) { sh[wid] = s; sh[4 + wid] = q; }
  __syncthreads();
  if (t == 0) {
    const float S = sh[0] + sh[1] + sh[2] + sh[3];
    const float Q = sh[4] + sh[5] + sh[6] + sh[7];
    const float mean = S * (1.f / 512.f);
    const float var = Q * (1.f / 512.f) - mean * mean;
    const float scale = gamma[c] / sqrtf(var + BN_EPS);
    param[0] = scale;
    param[1] = beta[c] - mean * scale;
  }
  __syncthreads();
  const float sc = param[0], sf = param[1];
  h[i0] = lrelu_f(v0 * sc + sf);
  h[i1] = lrelu_f(v1 * sc + sf);
}

extern "C" void kernel_launch(void* const* d_in, const int* in_sizes, int n_in,
                              void* d_out, int out_size, void* d_ws, size_t ws_size,
                              hipStream_t stream)
{
  (void)in_sizes; (void)n_in; (void)out_size; (void)ws_size;
  const float* x     = (const float*)d_in[0];
  const float* w_d0  = (const float*)d_in[1];
  const float* b_d0  = (const float*)d_in[2];
  const float* w_d1  = (const float*)d_in[3];
  const float* b_d1  = (const float*)d_in[4];
  const float* w_d2  = (const float*)d_in[5];
  const float* b_d2  = (const float*)d_in[6];
  const float* w_d3  = (const float*)d_in[7];
  const float* b_d3  = (const float*)d_in[8];
  const float* w_d4  = (const float*)d_in[9];
  const float* b_d4  = (const float*)d_in[10];
  const float* w_in  = (const float*)d_in[11];
  const float* b_in  = (const float*)d_in[12];
  const float* gamma = (const float*)d_in[13];
  const float* beta  = (const float*)d_in[14];
  const float* w_u0  = (const float*)d_in[15];
  const float* b_u0  = (const float*)d_in[16];
  const float* w_u1  = (const float*)d_in[17];
  const float* b_u1  = (const float*)d_in[18];
  const float* w_u2  = (const float*)d_in[19];
  const float* b_u2  = (const float*)d_in[20];
  const float* w_u3  = (const float*)d_in[21];
  const float* b_u3  = (const float*)d_in[22];
  const float* w_u4  = (const float*)d_in[23];
  const float* b_u4  = (const float*)d_in[24];
  const float* w_ep  = (const float*)d_in[25];
  const float* b_ep  = (const float*)d_in[26];

  // ---- explicit 64 MiB workspace map (offsets in floats; 1 MiB = 262144) ----
  float* W = (float*)d_ws;
  float* e0   = W;                  // [0,32MiB)   2x64x256x256
  float* e1   = W + 8388608;        // [32,48)     2x128x128x128
  float* Pd2  = W;                  // [0,16)      2 segs x 8MiB
  float* e2   = W + 12582912;       // [48,56)     2x256x64x64
  float* Pd3  = W + 4194304;        // [16,32)     4 segs x 4MiB
  float* e3   = W;                  // [0,4)
  float* Pd4  = W + 4194304;        // [16,32)     8 segs x 2MiB
  float* e4   = W + 1048576;        // [4,6)
  float* Pin  = W + 4194304;        // [16,32)     8 segs x 2MiB
  float* Fb   = W + 1572864;        // [6,8)       bn buffer
  float* G    = W;                  // [0,4)       u0 out
  float* Pu0  = W + 2097152;        // [8,40)      8 segs x 4MiB
  float* H    = W + 10485760;       // [40,48)     u1 out
  float* Pu1  = W + 1048576;        // [4,36)      4 segs x 8MiB
  float* I    = W + 12582912;       // [48,64)     u2 out
  float* Pu2  = W;                  // [0,32)      2 segs x 16MiB
  float* J    = W;                  // [0,32)      u3 out
  float* outp = (float*)d_out;

  const dim3 blk(256);
  // -------- encoder (conv+lrelu+down2 fused, 8-wide) --------
  conv3_kernel<1, 8, false><<<dim3(512,   1, 2), blk, 0, stream>>>(x,  w_d0, b_d0, e0,    3, 512, 512,   64, 256, 256, 1,   3,  1, 0);
  conv3_kernel<1, 8, false><<<dim3(128,   2, 2), blk, 0, stream>>>(e0, w_d1, b_d1, e1,   64, 256, 256,  128, 128, 128, 1,  64,  2, 0);
  conv3_kernel<1, 8, true ><<<dim3( 32,   8, 2), blk, 0, stream>>>(e1, w_d2, b_d2, Pd2, 128, 128, 128,  256,  64,  64, 1,  64,  4, 2097152);
  reduce_bias_act_kernel<<<dim3(2048), blk, 0, stream>>>(e2, Pd2, b_d2, 524288, 4096, 256, 2, 524288, 1);
  conv3_kernel<1, 8, true ><<<dim3(  8,  32, 2), blk, 0, stream>>>(e2, w_d3, b_d3, Pd3, 256,  64,  64,  512,  32,  32, 1,  64,  8, 1048576);
  reduce_bias_act_kernel<<<dim3(1024), blk, 0, stream>>>(e3, Pd3, b_d3, 262144, 1024, 512, 4, 262144, 1);
  conv3_kernel<1, 8, true ><<<dim3(  2, 128, 2), blk, 0, stream>>>(e3, w_d4, b_d4, Pd4, 512,  32,  32, 1024,  16,  16, 1,  64, 16, 524288);
  reduce_bias_act_kernel<<<dim3( 512), blk, 0, stream>>>(e4, Pd4, b_d4, 131072, 256, 1024, 8, 131072, 1);
  // -------- innermost conv (no act) + BN + lrelu --------
  conv3_kernel<0, 8, true ><<<dim3(  2, 128, 2), blk, 0, stream>>>(e4, w_in, b_in, Pin, 1024, 16,  16, 1024,  16,  16, 0, 128, 16, 524288);
  reduce_bias_act_kernel<<<dim3( 512), blk, 0, stream>>>(Fb, Pin, b_in, 131072, 256, 1024, 8, 131072, 0);
  bn_lrelu_kernel<<<dim3(1024), blk, 0, stream>>>(Fb, gamma, beta);
  // -------- decoder (parity-decomposed up2+conv+lrelu, NQ=2) --------
  up_conv_kernel<2, 4, 8, false, true ><<<dim3(  4, 64, 2), blk, 0, stream>>>(Fb, w_u0, b_u0, Pu0, 1024, 16,  16,  512,  32,  32, 128, 8, 1048576, nullptr, nullptr);
  reduce_bias_act_kernel<<<dim3(1024), blk, 0, stream>>>(G, Pu0, b_u0, 262144, 1024, 512, 8, 262144, 1);
  up_conv_kernel<2, 4, 8, false, true ><<<dim3( 16, 16, 2), blk, 0, stream>>>(G,  w_u1, b_u1, Pu1,  512, 32,  32,  256,  64,  64, 128, 4, 2097152, nullptr, nullptr);
  reduce_bias_act_kernel<<<dim3(2048), blk, 0, stream>>>(H, Pu1, b_u1, 524288, 4096, 256, 4, 524288, 1);
  up_conv_kernel<2, 4, 8, false, true ><<<dim3( 64,  4, 2), blk, 0, stream>>>(H,  w_u2, b_u2, Pu2,  256, 64,  64,  128, 128, 128, 128, 2, 4194304, nullptr, nullptr);
  reduce_bias_act_kernel<<<dim3(4096), blk, 0, stream>>>(I, Pu2, b_u2, 1048576, 16384, 128, 2, 1048576, 1);
  up_conv_kernel<2, 4, 8, false, false><<<dim3(256,  1, 2), blk, 0, stream>>>(I,  w_u3, b_u3, J,    128, 128, 128,   64, 256, 256, 128, 1, 0, nullptr, nullptr);
  // -------- u4 + fused 1x1 epilogue -> d_out --------
  up_conv_kernel<2, 4, 8, true,  false><<<dim3(1024, 1, 2), blk, 0, stream>>>(J,  w_u4, b_u4, outp,  64, 256, 256,   64, 512, 512,  64, 1, 0, w_ep, b_ep);
}